// Round 2
// baseline (415.925 us; speedup 1.0000x reference)
//
#include <hip/hip_runtime.h>
#include <math.h>

// N = 20000, E = 640000, IN_DIM = HID = 128, OUT = 64
// Activations bf16 (ushort bits), accumulation fp32 via MFMA 16x16x32.

typedef __attribute__((ext_vector_type(8))) short short8;
typedef __attribute__((ext_vector_type(4))) float floatx4;

__device__ __forceinline__ unsigned short f2b(float f) {
    unsigned u = __float_as_uint(f);
    unsigned r = (u + 0x7fffu + ((u >> 16) & 1u)) >> 16;
    return (unsigned short)r;
}
__device__ __forceinline__ float b2f(unsigned short h) {
    return __uint_as_float(((unsigned)h) << 16);
}
__device__ __forceinline__ float b2f_lo(unsigned v) {
    return __uint_as_float(v << 16);
}
__device__ __forceinline__ float b2f_hi(unsigned v) {
    return __uint_as_float(v & 0xffff0000u);
}
__device__ __forceinline__ floatx4 MFMA(short8 a, short8 b, floatx4 c) {
    return __builtin_amdgcn_mfma_f32_16x16x32_bf16(a, b, c, 0, 0, 0);
}
__device__ __forceinline__ float gelu_exact(float x) {
    return 0.5f * x * (1.0f + erff(x * 0.70710678118654752440f));
}

// B fragment for (ct, ks) at lane: packed W layout
#define FRAG(P, ct, ks, lane) (*(const short8*)((P) + (((((ct)*4 + (ks))*64) + (lane)) << 3)))

// ---------------- count (fire-and-forget) + weight pack + last-block scan ---
// The last block to finish performs the full global prefix scan of cnt,
// emitting row_ptr (global offsets, row_ptr[N]=E), cursor (= row_ptr copy
// for the fill pass), and dinv = rsqrt(deg+1).

__global__ __launch_bounds__(256) void count_pack_scan_kernel(
    const int* __restrict__ eidx, int E, int N,
    int* __restrict__ cnt, int* __restrict__ done,
    int* __restrict__ row_ptr, int* __restrict__ cursor, float* __restrict__ dinv,
    const float* Wg, const float* Wsl, const float* Wsr,
    const float* W1, const float* W2, const float* W3,
    unsigned short* Pg, unsigned short* Psl, unsigned short* Psr,
    unsigned short* P1, unsigned short* P2, unsigned short* P3,
    int countBlocks, int totalBlocks)
{
    __shared__ int sh[256];
    __shared__ int isLast;

    if ((int)blockIdx.x < countBlocks) {
        int e = blockIdx.x * 256 + threadIdx.x;
        if (e < E) atomicAdd(&cnt[eidx[E + e]], 1);   // no return -> fire & forget
    } else {
        int t = (blockIdx.x - countBlocks) * 256 + threadIdx.x;
        if (t < 11264) {
            const float* W; unsigned short* P; int NC = 128; int base;
            if (t < 2048)       { W = Wg;  P = Pg;  base = t; }
            else if (t < 4096)  { W = Wsl; P = Psl; base = t - 2048; }
            else if (t < 6144)  { W = Wsr; P = Psr; base = t - 4096; }
            else if (t < 8192)  { W = W1;  P = P1;  base = t - 6144; }
            else if (t < 10240) { W = W2;  P = P2;  base = t - 8192; }
            else                { W = W3;  P = P3;  base = t - 10240; NC = 64; }
            int l  = base & 63;
            int ks = (base >> 6) & 3;
            int ct = base >> 8;
            int n  = ct * 16 + (l & 15);
            int k0 = ks * 32 + ((l >> 4) << 3);
            short8 v;
            #pragma unroll
            for (int j = 0; j < 8; j++) v[j] = (short)f2b(W[(size_t)(k0 + j) * NC + n]);
            *(short8*)(P + ((size_t)base << 3)) = v;
        }
    }

    // ---- decoupled completion: last block does the scan ----
    __threadfence();
    __syncthreads();
    if (threadIdx.x == 0)
        isLast = (atomicAdd(done, 1) == totalBlocks - 1) ? 1 : 0;
    __syncthreads();
    if (!isLast) return;
    __threadfence();

    int tid = threadIdx.x;
    int CH = (N + 255) >> 8;           // 79 for N=20000
    int t0 = tid * CH;
    int sum = 0;
    for (int i = 0; i < CH; i++) {
        int idx = t0 + i;
        if (idx < N) sum += cnt[idx];
    }
    sh[tid] = sum;
    __syncthreads();
    for (int off = 1; off < 256; off <<= 1) {
        int v = (tid >= off) ? sh[tid - off] : 0;
        __syncthreads();
        sh[tid] += v;
        __syncthreads();
    }
    int run = sh[tid] - sum;           // exclusive prefix of this chunk
    for (int i = 0; i < CH; i++) {
        int idx = t0 + i;
        if (idx < N) {
            int c = cnt[idx];
            row_ptr[idx] = run;
            cursor[idx]  = run;
            dinv[idx] = rsqrtf((float)(c + 1));
            run += c;
        }
    }
    if (tid == 0) row_ptr[N] = E;
}

// ---------------- fill (cursor atomics) + GCN GEMM (dinv pre-folded) -------

__global__ __launch_bounds__(256) void fill_gemm_kernel(
    const int* __restrict__ eidx, int E,
    int* __restrict__ cursor, int* __restrict__ col,
    const float* __restrict__ feat, const float* __restrict__ dinv,
    const unsigned short* __restrict__ Pg,
    unsigned short* __restrict__ xs, int M, int fillBlocks)
{
    if ((int)blockIdx.x < fillBlocks) {
        int e = blockIdx.x * 256 + threadIdx.x;
        if (e < E) {
            int d = eidx[E + e];
            int pos = atomicAdd(&cursor[d], 1);
            col[pos] = eidx[e];
        }
        return;
    }
    // GCN GEMM: wave computes 16 rows x 64 cols of xs = bf16(dinv[row] * (feat @ Wg))
    int bid = blockIdx.x - fillBlocks;
    int w = bid * 4 + (threadIdx.x >> 6);
    if (w >= (M / 16) * 2) return;
    int lane = threadIdx.x & 63;
    int m = lane & 15, quad = lane >> 4;
    int rt = w >> 1, ch = w & 1;
    const float* arow = feat + (size_t)(rt * 16 + m) * 128;
    short8 a[4];
    #pragma unroll
    for (int ks = 0; ks < 4; ks++) {
        float4 f0 = *(const float4*)(arow + ks * 32 + quad * 8);
        float4 f1 = *(const float4*)(arow + ks * 32 + quad * 8 + 4);
        short8 s;
        s[0] = (short)f2b(f0.x); s[1] = (short)f2b(f0.y);
        s[2] = (short)f2b(f0.z); s[3] = (short)f2b(f0.w);
        s[4] = (short)f2b(f1.x); s[5] = (short)f2b(f1.y);
        s[6] = (short)f2b(f1.z); s[7] = (short)f2b(f1.w);
        a[ks] = s;
    }
    float4 dvv = *(const float4*)(dinv + rt * 16 + quad * 4);
    float dv[4] = {dvv.x, dvv.y, dvv.z, dvv.w};
    #pragma unroll
    for (int ct = 0; ct < 4; ct++) {
        floatx4 acc = {0.f, 0.f, 0.f, 0.f};
        #pragma unroll
        for (int ks = 0; ks < 4; ks++)
            acc = MFMA(a[ks], FRAG(Pg, ch * 4 + ct, ks, lane), acc);
        #pragma unroll
        for (int reg = 0; reg < 4; reg++)
            xs[(size_t)(rt * 16 + quad * 4 + reg) * 128 + (ch * 4 + ct) * 16 + m] =
                f2b(acc[reg] * dv[reg]);
    }
}

// ---------------- aggregation: 16 lanes per edge-row, direct col broadcast --
// GCN:  xs pre-scaled by dinv[s]; h1[d] = relu(dinv[d]*(sum_s xs[s] + xs[d]) + b)
// SAGE: mean[d] = (1/max(deg,1)) * sum_s h1[s]

template<bool GCN>
__global__ __launch_bounds__(256) void agg_kernel(
    const unsigned short* __restrict__ X, const int* __restrict__ row_ptr,
    const int* __restrict__ col, const float* __restrict__ dinv,
    const float* __restrict__ bias,
    unsigned short* __restrict__ Y, int N)
{
    int w = (int)((blockIdx.x * 256 + threadIdx.x) >> 6);
    if (w >= N) return;
    int lane = threadIdx.x & 63;
    int g = lane >> 4, t = lane & 15;
    const uint4* Xq = (const uint4*)X;

    int beg = row_ptr[w], end = row_ptr[w + 1];
    int deg = end - beg;

    float acc[8] = {0.f, 0.f, 0.f, 0.f, 0.f, 0.f, 0.f, 0.f};

    int e = beg + g;
    for (; e + 4 < end; e += 8) {
        int s0 = col[e];
        int s1 = col[e + 4];
        uint4 q0 = Xq[(size_t)s0 * 16 + t];
        uint4 q1 = Xq[(size_t)s1 * 16 + t];
        acc[0] += b2f_lo(q0.x); acc[1] += b2f_hi(q0.x);
        acc[2] += b2f_lo(q0.y); acc[3] += b2f_hi(q0.y);
        acc[4] += b2f_lo(q0.z); acc[5] += b2f_hi(q0.z);
        acc[6] += b2f_lo(q0.w); acc[7] += b2f_hi(q0.w);
        acc[0] += b2f_lo(q1.x); acc[1] += b2f_hi(q1.x);
        acc[2] += b2f_lo(q1.y); acc[3] += b2f_hi(q1.y);
        acc[4] += b2f_lo(q1.z); acc[5] += b2f_hi(q1.z);
        acc[6] += b2f_lo(q1.w); acc[7] += b2f_hi(q1.w);
    }
    if (e < end) {
        int s0 = col[e];
        uint4 q0 = Xq[(size_t)s0 * 16 + t];
        acc[0] += b2f_lo(q0.x); acc[1] += b2f_hi(q0.x);
        acc[2] += b2f_lo(q0.y); acc[3] += b2f_hi(q0.y);
        acc[4] += b2f_lo(q0.z); acc[5] += b2f_hi(q0.z);
        acc[6] += b2f_lo(q0.w); acc[7] += b2f_hi(q0.w);
    }

    // reduce across the 4 groups
    #pragma unroll
    for (int i = 0; i < 8; i++) {
        acc[i] += __shfl_xor(acc[i], 16);
        acc[i] += __shfl_xor(acc[i], 32);
    }
    if (g == 0) {
        float out[8];
        if (GCN) {
            float dw = dinv[w];
            uint4 q = Xq[(size_t)w * 16 + t];  // self loop (pre-scaled by dinv[w])
            acc[0] += b2f_lo(q.x); acc[1] += b2f_hi(q.x);
            acc[2] += b2f_lo(q.y); acc[3] += b2f_hi(q.y);
            acc[4] += b2f_lo(q.z); acc[5] += b2f_hi(q.z);
            acc[6] += b2f_lo(q.w); acc[7] += b2f_hi(q.w);
            float4 b0 = *(const float4*)(bias + t * 8);
            float4 b1 = *(const float4*)(bias + t * 8 + 4);
            out[0] = fmaxf(fmaf(acc[0], dw, b0.x), 0.f);
            out[1] = fmaxf(fmaf(acc[1], dw, b0.y), 0.f);
            out[2] = fmaxf(fmaf(acc[2], dw, b0.z), 0.f);
            out[3] = fmaxf(fmaf(acc[3], dw, b0.w), 0.f);
            out[4] = fmaxf(fmaf(acc[4], dw, b1.x), 0.f);
            out[5] = fmaxf(fmaf(acc[5], dw, b1.y), 0.f);
            out[6] = fmaxf(fmaf(acc[6], dw, b1.z), 0.f);
            out[7] = fmaxf(fmaf(acc[7], dw, b1.w), 0.f);
        } else {
            float rc = 1.0f / (float)(deg > 0 ? deg : 1);
            #pragma unroll
            for (int i = 0; i < 8; i++) out[i] = acc[i] * rc;
        }
        uint4 r;
        r.x = (unsigned)f2b(out[0]) | ((unsigned)f2b(out[1]) << 16);
        r.y = (unsigned)f2b(out[2]) | ((unsigned)f2b(out[3]) << 16);
        r.z = (unsigned)f2b(out[4]) | ((unsigned)f2b(out[5]) << 16);
        r.w = (unsigned)f2b(out[6]) | ((unsigned)f2b(out[7]) << 16);
        ((uint4*)Y)[(size_t)w * 16 + t] = r;
    }
}

// ---------------- fused SAGE + policy MLP + value head ----------------
// Per wave: 16 rows. h2 = relu(mean@Wsl + h1@Wsr + bsl) stays in LDS;
// then gelu(W1), gelu(W2), W3 -> means; value = h2@Wv+bv from C-layout.

__global__ __launch_bounds__(256) void sage_mlp_kernel(
    const unsigned short* __restrict__ mean, const unsigned short* __restrict__ h1,
    const unsigned short* __restrict__ Psl, const unsigned short* __restrict__ Psr,
    const float* __restrict__ bsl,
    const unsigned short* __restrict__ P1, const float* __restrict__ b1,
    const unsigned short* __restrict__ P2, const float* __restrict__ b2,
    const unsigned short* __restrict__ P3, const float* __restrict__ b3,
    const float* __restrict__ Wv, const float* __restrict__ bv,
    float* __restrict__ means, float* __restrict__ values, int M)
{
    __shared__ unsigned short z[4][16 * 136];
    int widx = threadIdx.x >> 6, lane = threadIdx.x & 63;
    int w = blockIdx.x * 4 + widx;
    if (w >= M / 16) return;
    int m = lane & 15, quad = lane >> 4;
    unsigned short* zt = &z[widx][0];
    int r0 = w * 16;

    short8 am[4], ar[4];
    #pragma unroll
    for (int ks = 0; ks < 4; ks++) {
        am[ks] = *(const short8*)(mean + (size_t)(r0 + m) * 128 + ks * 32 + quad * 8);
        ar[ks] = *(const short8*)(h1   + (size_t)(r0 + m) * 128 + ks * 32 + quad * 8);
    }

    // SAGE layer: h2 -> LDS (bf16) + value-head partials from C-layout
    float vpart[4] = {0.f, 0.f, 0.f, 0.f};
    #pragma unroll
    for (int ct = 0; ct < 8; ct++) {
        floatx4 acc = {0.f, 0.f, 0.f, 0.f};
        #pragma unroll
        for (int ks = 0; ks < 4; ks++) acc = MFMA(am[ks], FRAG(Psl, ct, ks, lane), acc);
        #pragma unroll
        for (int ks = 0; ks < 4; ks++) acc = MFMA(ar[ks], FRAG(Psr, ct, ks, lane), acc);
        float bb = bsl[ct * 16 + m];
        float wv = Wv[ct * 16 + m];
        #pragma unroll
        for (int reg = 0; reg < 4; reg++) {
            float o = fmaxf(acc[reg] + bb, 0.f);
            vpart[reg] = fmaf(o, wv, vpart[reg]);
            zt[(quad * 4 + reg) * 136 + ct * 16 + m] = f2b(o);
        }
    }
    // value: reduce across m-lanes within each quad
    #pragma unroll
    for (int off = 1; off <= 8; off <<= 1) {
        #pragma unroll
        for (int reg = 0; reg < 4; reg++)
            vpart[reg] += __shfl_xor(vpart[reg], off);
    }
    if (m == 0) {
        float bvv = bv[0];
        #pragma unroll
        for (int reg = 0; reg < 4; reg++)
            values[r0 + quad * 4 + reg] = vpart[reg] + bvv;
    }

    short8 a1[4];
    #pragma unroll
    for (int ks = 0; ks < 4; ks++)
        a1[ks] = *(const short8*)(zt + m * 136 + ks * 32 + quad * 8);

    // layer 1: gelu(h2 @ W1 + b1) -> LDS
    #pragma unroll
    for (int ct = 0; ct < 8; ct++) {
        floatx4 acc = {0.f, 0.f, 0.f, 0.f};
        #pragma unroll
        for (int ks = 0; ks < 4; ks++) acc = MFMA(a1[ks], FRAG(P1, ct, ks, lane), acc);
        float bb = b1[ct * 16 + m];
        #pragma unroll
        for (int reg = 0; reg < 4; reg++)
            zt[(quad * 4 + reg) * 136 + ct * 16 + m] = f2b(gelu_exact(acc[reg] + bb));
    }
    short8 a2[4];
    #pragma unroll
    for (int ks = 0; ks < 4; ks++)
        a2[ks] = *(const short8*)(zt + m * 136 + ks * 32 + quad * 8);

    // layer 2: gelu(z1 @ W2 + b2) -> LDS
    #pragma unroll
    for (int ct = 0; ct < 8; ct++) {
        floatx4 acc = {0.f, 0.f, 0.f, 0.f};
        #pragma unroll
        for (int ks = 0; ks < 4; ks++) acc = MFMA(a2[ks], FRAG(P2, ct, ks, lane), acc);
        float bb = b2[ct * 16 + m];
        #pragma unroll
        for (int reg = 0; reg < 4; reg++)
            zt[(quad * 4 + reg) * 136 + ct * 16 + m] = f2b(gelu_exact(acc[reg] + bb));
    }
    short8 a3[4];
    #pragma unroll
    for (int ks = 0; ks < 4; ks++)
        a3[ks] = *(const short8*)(zt + m * 136 + ks * 32 + quad * 8);

    // layer 3: means = z2 @ W3 + b3  (64 cols)
    #pragma unroll
    for (int ct = 0; ct < 4; ct++) {
        floatx4 acc = {0.f, 0.f, 0.f, 0.f};
        #pragma unroll
        for (int ks = 0; ks < 4; ks++) acc = MFMA(a3[ks], FRAG(P3, ct, ks, lane), acc);
        float bb = b3[ct * 16 + m];
        #pragma unroll
        for (int reg = 0; reg < 4; reg++)
            means[(size_t)(r0 + quad * 4 + reg) * 64 + ct * 16 + m] = acc[reg] + bb;
    }
}

// ---------------- launch ----------------

extern "C" void kernel_launch(void* const* d_in, const int* in_sizes, int n_in,
                              void* d_out, int out_size, void* d_ws, size_t ws_size,
                              hipStream_t stream) {
    const float* feat  = (const float*)d_in[0];
    const int*   eidx  = (const int*)d_in[1];
    const float* W_gcn = (const float*)d_in[2];
    const float* b_gcn = (const float*)d_in[3];
    const float* W_sl  = (const float*)d_in[4];
    const float* b_sl  = (const float*)d_in[5];
    const float* W_sr  = (const float*)d_in[6];
    const float* W1    = (const float*)d_in[7];
    const float* b1    = (const float*)d_in[8];
    const float* W2    = (const float*)d_in[9];
    const float* b2    = (const float*)d_in[10];
    const float* W3    = (const float*)d_in[11];
    const float* b3    = (const float*)d_in[12];
    const float* Wv    = (const float*)d_in[13];
    const float* bv    = (const float*)d_in[14];

    const int N = in_sizes[0] / 128;
    const int E = in_sizes[1] / 2;

    char* ws = (char*)d_ws;
    size_t off = 0;
    auto alloc = [&](size_t bytes) -> void* {
        void* p = ws + off;
        off += (bytes + 255) & ~(size_t)255;
        return p;
    };
    int*   cnt     = (int*)alloc((size_t)(N + 64) * 4);   // done counter lives at cnt+N
    int*   done    = cnt + N;
    int*   row_ptr = (int*)alloc((size_t)(N + 1) * 4);
    int*   cursor  = (int*)alloc((size_t)N * 4);
    float* dinv    = (float*)alloc((size_t)N * 4);
    int*   col     = (int*)alloc((size_t)E * 4);
    unsigned short* xs   = (unsigned short*)alloc((size_t)N * 128 * 2);
    unsigned short* h1   = (unsigned short*)alloc((size_t)N * 128 * 2);
    unsigned short* mean = (unsigned short*)alloc((size_t)N * 128 * 2);
    unsigned short* Pg   = (unsigned short*)alloc(2048 * 8 * 2);
    unsigned short* Psl  = (unsigned short*)alloc(2048 * 8 * 2);
    unsigned short* Psr  = (unsigned short*)alloc(2048 * 8 * 2);
    unsigned short* P1   = (unsigned short*)alloc(2048 * 8 * 2);
    unsigned short* P2   = (unsigned short*)alloc(2048 * 8 * 2);
    unsigned short* P3   = (unsigned short*)alloc(1024 * 8 * 2);

    hipMemsetAsync(cnt, 0, (size_t)(N + 64) * 4, stream);  // zeroes cnt + done

    const int countBlocks = (E + 255) / 256;               // 2500
    const int packBlocks  = (11264 + 255) / 256;           // 44
    const int totalBlocks = countBlocks + packBlocks;
    count_pack_scan_kernel<<<totalBlocks, 256, 0, stream>>>(
        eidx, E, N, cnt, done, row_ptr, cursor, dinv,
        W_gcn, W_sl, W_sr, W1, W2, W3,
        Pg, Psl, Psr, P1, P2, P3, countBlocks, totalBlocks);

    const int fillBlocks = (E + 255) / 256;                // 2500
    const int gemmBlocks = ((N / 16) * 2 + 3) / 4;         // 625
    fill_gemm_kernel<<<fillBlocks + gemmBlocks, 256, 0, stream>>>(
        eidx, E, cursor, col, feat, dinv, Pg, xs, N, fillBlocks);

    const int agrid = (N + 3) / 4;
    agg_kernel<true><<<agrid, 256, 0, stream>>>(xs, row_ptr, col, dinv, b_gcn, h1, N);
    agg_kernel<false><<<agrid, 256, 0, stream>>>(h1, row_ptr, col, dinv, nullptr, mean, N);

    sage_mlp_kernel<<<(N / 16 + 3) / 4, 256, 0, stream>>>(
        mean, h1, Psl, Psr, b_sl, P1, b1, P2, b2, P3, b3, Wv, bv,
        (float*)d_out, (float*)d_out + (size_t)N * 64, N);
}

// Round 3
// 290.605 us; speedup vs baseline: 1.4312x; 1.4312x over previous
//
#include <hip/hip_runtime.h>
#include <math.h>

// N = 20000, E = 640000, IN_DIM = HID = 128, OUT = 64
// Activations bf16 (ushort bits), accumulation fp32 via MFMA 16x16x32.

typedef __attribute__((ext_vector_type(8))) short short8;
typedef __attribute__((ext_vector_type(4))) float floatx4;

__device__ __forceinline__ unsigned short f2b(float f) {
    unsigned u = __float_as_uint(f);
    unsigned r = (u + 0x7fffu + ((u >> 16) & 1u)) >> 16;
    return (unsigned short)r;
}
__device__ __forceinline__ float b2f(unsigned short h) {
    return __uint_as_float(((unsigned)h) << 16);
}
__device__ __forceinline__ float b2f_lo(unsigned v) {
    return __uint_as_float(v << 16);
}
__device__ __forceinline__ float b2f_hi(unsigned v) {
    return __uint_as_float(v & 0xffff0000u);
}
__device__ __forceinline__ floatx4 MFMA(short8 a, short8 b, floatx4 c) {
    return __builtin_amdgcn_mfma_f32_16x16x32_bf16(a, b, c, 0, 0, 0);
}
__device__ __forceinline__ float gelu_exact(float x) {
    return 0.5f * x * (1.0f + erff(x * 0.70710678118654752440f));
}

// B fragment for (ct, ks) at lane: packed W layout
#define FRAG(P, ct, ks, lane) (*(const short8*)((P) + (((((ct)*4 + (ks))*64) + (lane)) << 3)))

// ---------------- count (fire-and-forget atomics) + weight packing ---------
// NO fences, NO done-counter: visibility to later dispatches comes from the
// implicit end-of-kernel release. (Round-1 lesson: per-block __threadfence
// costs an L2 writeback each -> +180us across 2544 blocks.)

__global__ __launch_bounds__(256) void count_pack_kernel(
    const int* __restrict__ eidx, int E,
    int* __restrict__ cnt,
    const float* Wg, const float* Wsl, const float* Wsr,
    const float* W1, const float* W2, const float* W3,
    unsigned short* Pg, unsigned short* Psl, unsigned short* Psr,
    unsigned short* P1, unsigned short* P2, unsigned short* P3,
    int countBlocks)
{
    if ((int)blockIdx.x < countBlocks) {
        int e = blockIdx.x * 256 + threadIdx.x;
        if (e < E) atomicAdd(&cnt[eidx[E + e]], 1);   // no return -> fire & forget
        return;
    }
    int t = (blockIdx.x - countBlocks) * 256 + threadIdx.x;
    const float* W; unsigned short* P; int NC = 128; int base;
    if (t < 2048)       { W = Wg;  P = Pg;  base = t; }
    else if (t < 4096)  { W = Wsl; P = Psl; base = t - 2048; }
    else if (t < 6144)  { W = Wsr; P = Psr; base = t - 4096; }
    else if (t < 8192)  { W = W1;  P = P1;  base = t - 6144; }
    else if (t < 10240) { W = W2;  P = P2;  base = t - 8192; }
    else if (t < 11264) { W = W3;  P = P3;  base = t - 10240; NC = 64; }
    else return;
    int l  = base & 63;
    int ks = (base >> 6) & 3;
    int ct = base >> 8;
    int n  = ct * 16 + (l & 15);
    int k0 = ks * 32 + ((l >> 4) << 3);
    short8 v;
    #pragma unroll
    for (int j = 0; j < 8; j++) v[j] = (short)f2b(W[(size_t)(k0 + j) * NC + n]);
    *(short8*)(P + ((size_t)base << 3)) = v;
}

// ---------------- single-workgroup global scan ----------------
// 256 threads x 79 contiguous elements each: chunk sums -> block scan ->
// emit GLOBAL row_ptr (row_ptr[N]=E), cursor copy, dinv = rsqrt(deg+1).
// No bsums, so fill/agg need no serial prefix loops.

__global__ __launch_bounds__(256) void scan_kernel(
    const int* __restrict__ cnt, int N, int E,
    int* __restrict__ row_ptr, int* __restrict__ cursor, float* __restrict__ dinv)
{
    __shared__ int sh[256];
    int tid = threadIdx.x;
    int CH = (N + 255) >> 8;           // 79 for N=20000
    int t0 = tid * CH;
    int sum = 0;
    for (int i = 0; i < CH; i++) {
        int idx = t0 + i;
        if (idx < N) sum += cnt[idx];
    }
    sh[tid] = sum;
    __syncthreads();
    for (int off = 1; off < 256; off <<= 1) {
        int v = (tid >= off) ? sh[tid - off] : 0;
        __syncthreads();
        sh[tid] += v;
        __syncthreads();
    }
    int run = sh[tid] - sum;           // exclusive prefix of this chunk
    for (int i = 0; i < CH; i++) {
        int idx = t0 + i;
        if (idx < N) {
            int c = cnt[idx];          // L2-warm reread
            row_ptr[idx] = run;
            cursor[idx]  = run;
            dinv[idx] = rsqrtf((float)(c + 1));
            run += c;
        }
    }
    if (tid == 0) row_ptr[N] = E;
}

// ---------------- fill (cursor atomics) + GCN GEMM (dinv pre-folded) -------

__global__ __launch_bounds__(256) void fill_gemm_kernel(
    const int* __restrict__ eidx, int E,
    int* __restrict__ cursor, int* __restrict__ col,
    const float* __restrict__ feat, const float* __restrict__ dinv,
    const unsigned short* __restrict__ Pg,
    unsigned short* __restrict__ xs, int M, int fillBlocks)
{
    if ((int)blockIdx.x < fillBlocks) {
        int e = blockIdx.x * 256 + threadIdx.x;
        if (e < E) {
            int d = eidx[E + e];
            int pos = atomicAdd(&cursor[d], 1);
            col[pos] = eidx[e];
        }
        return;
    }
    // GCN GEMM: wave computes 16 rows x 64 cols of xs = bf16(dinv[row] * (feat @ Wg))
    int bid = blockIdx.x - fillBlocks;
    int w = bid * 4 + (threadIdx.x >> 6);
    if (w >= (M / 16) * 2) return;
    int lane = threadIdx.x & 63;
    int m = lane & 15, quad = lane >> 4;
    int rt = w >> 1, ch = w & 1;
    const float* arow = feat + (size_t)(rt * 16 + m) * 128;
    short8 a[4];
    #pragma unroll
    for (int ks = 0; ks < 4; ks++) {
        float4 f0 = *(const float4*)(arow + ks * 32 + quad * 8);
        float4 f1 = *(const float4*)(arow + ks * 32 + quad * 8 + 4);
        short8 s;
        s[0] = (short)f2b(f0.x); s[1] = (short)f2b(f0.y);
        s[2] = (short)f2b(f0.z); s[3] = (short)f2b(f0.w);
        s[4] = (short)f2b(f1.x); s[5] = (short)f2b(f1.y);
        s[6] = (short)f2b(f1.z); s[7] = (short)f2b(f1.w);
        a[ks] = s;
    }
    float4 dvv = *(const float4*)(dinv + rt * 16 + quad * 4);
    float dv[4] = {dvv.x, dvv.y, dvv.z, dvv.w};
    #pragma unroll
    for (int ct = 0; ct < 4; ct++) {
        floatx4 acc = {0.f, 0.f, 0.f, 0.f};
        #pragma unroll
        for (int ks = 0; ks < 4; ks++)
            acc = MFMA(a[ks], FRAG(Pg, ch * 4 + ct, ks, lane), acc);
        #pragma unroll
        for (int reg = 0; reg < 4; reg++)
            xs[(size_t)(rt * 16 + quad * 4 + reg) * 128 + (ch * 4 + ct) * 16 + m] =
                f2b(acc[reg] * dv[reg]);
    }
}

// ---------------- aggregation: 16 lanes per edge-row, direct col broadcast --
// GCN:  xs pre-scaled by dinv[s]; h1[d] = relu(dinv[d]*(sum_s xs[s] + xs[d]) + b)
// SAGE: mean[d] = (1/max(deg,1)) * sum_s h1[s]

template<bool GCN>
__global__ __launch_bounds__(256) void agg_kernel(
    const unsigned short* __restrict__ X, const int* __restrict__ row_ptr,
    const int* __restrict__ col, const float* __restrict__ dinv,
    const float* __restrict__ bias,
    unsigned short* __restrict__ Y, int N)
{
    int w = (int)((blockIdx.x * 256 + threadIdx.x) >> 6);
    if (w >= N) return;
    int lane = threadIdx.x & 63;
    int g = lane >> 4, t = lane & 15;
    const uint4* Xq = (const uint4*)X;

    int beg = row_ptr[w], end = row_ptr[w + 1];
    int deg = end - beg;

    float acc[8] = {0.f, 0.f, 0.f, 0.f, 0.f, 0.f, 0.f, 0.f};

    int e = beg + g;
    for (; e + 4 < end; e += 8) {
        int s0 = col[e];
        int s1 = col[e + 4];
        uint4 q0 = Xq[(size_t)s0 * 16 + t];
        uint4 q1 = Xq[(size_t)s1 * 16 + t];
        acc[0] += b2f_lo(q0.x); acc[1] += b2f_hi(q0.x);
        acc[2] += b2f_lo(q0.y); acc[3] += b2f_hi(q0.y);
        acc[4] += b2f_lo(q0.z); acc[5] += b2f_hi(q0.z);
        acc[6] += b2f_lo(q0.w); acc[7] += b2f_hi(q0.w);
        acc[0] += b2f_lo(q1.x); acc[1] += b2f_hi(q1.x);
        acc[2] += b2f_lo(q1.y); acc[3] += b2f_hi(q1.y);
        acc[4] += b2f_lo(q1.z); acc[5] += b2f_hi(q1.z);
        acc[6] += b2f_lo(q1.w); acc[7] += b2f_hi(q1.w);
    }
    if (e < end) {
        int s0 = col[e];
        uint4 q0 = Xq[(size_t)s0 * 16 + t];
        acc[0] += b2f_lo(q0.x); acc[1] += b2f_hi(q0.x);
        acc[2] += b2f_lo(q0.y); acc[3] += b2f_hi(q0.y);
        acc[4] += b2f_lo(q0.z); acc[5] += b2f_hi(q0.z);
        acc[6] += b2f_lo(q0.w); acc[7] += b2f_hi(q0.w);
    }

    // reduce across the 4 groups
    #pragma unroll
    for (int i = 0; i < 8; i++) {
        acc[i] += __shfl_xor(acc[i], 16);
        acc[i] += __shfl_xor(acc[i], 32);
    }
    if (g == 0) {
        float out[8];
        if (GCN) {
            float dw = dinv[w];
            uint4 q = Xq[(size_t)w * 16 + t];  // self loop (pre-scaled by dinv[w])
            acc[0] += b2f_lo(q.x); acc[1] += b2f_hi(q.x);
            acc[2] += b2f_lo(q.y); acc[3] += b2f_hi(q.y);
            acc[4] += b2f_lo(q.z); acc[5] += b2f_hi(q.z);
            acc[6] += b2f_lo(q.w); acc[7] += b2f_hi(q.w);
            float4 b0 = *(const float4*)(bias + t * 8);
            float4 b1 = *(const float4*)(bias + t * 8 + 4);
            out[0] = fmaxf(fmaf(acc[0], dw, b0.x), 0.f);
            out[1] = fmaxf(fmaf(acc[1], dw, b0.y), 0.f);
            out[2] = fmaxf(fmaf(acc[2], dw, b0.z), 0.f);
            out[3] = fmaxf(fmaf(acc[3], dw, b0.w), 0.f);
            out[4] = fmaxf(fmaf(acc[4], dw, b1.x), 0.f);
            out[5] = fmaxf(fmaf(acc[5], dw, b1.y), 0.f);
            out[6] = fmaxf(fmaf(acc[6], dw, b1.z), 0.f);
            out[7] = fmaxf(fmaf(acc[7], dw, b1.w), 0.f);
        } else {
            float rc = 1.0f / (float)(deg > 0 ? deg : 1);
            #pragma unroll
            for (int i = 0; i < 8; i++) out[i] = acc[i] * rc;
        }
        uint4 r;
        r.x = (unsigned)f2b(out[0]) | ((unsigned)f2b(out[1]) << 16);
        r.y = (unsigned)f2b(out[2]) | ((unsigned)f2b(out[3]) << 16);
        r.z = (unsigned)f2b(out[4]) | ((unsigned)f2b(out[5]) << 16);
        r.w = (unsigned)f2b(out[6]) | ((unsigned)f2b(out[7]) << 16);
        ((uint4*)Y)[(size_t)w * 16 + t] = r;
    }
}

// ---------------- fused SAGE + policy MLP + value head ----------------
// Per wave: 16 rows. h2 = relu(mean@Wsl + h1@Wsr + bsl) stays in LDS;
// then gelu(W1), gelu(W2), W3 -> means; value = h2@Wv+bv from C-layout.

__global__ __launch_bounds__(256) void sage_mlp_kernel(
    const unsigned short* __restrict__ mean, const unsigned short* __restrict__ h1,
    const unsigned short* __restrict__ Psl, const unsigned short* __restrict__ Psr,
    const float* __restrict__ bsl,
    const unsigned short* __restrict__ P1, const float* __restrict__ b1,
    const unsigned short* __restrict__ P2, const float* __restrict__ b2,
    const unsigned short* __restrict__ P3, const float* __restrict__ b3,
    const float* __restrict__ Wv, const float* __restrict__ bv,
    float* __restrict__ means, float* __restrict__ values, int M)
{
    __shared__ unsigned short z[4][16 * 136];
    int widx = threadIdx.x >> 6, lane = threadIdx.x & 63;
    int w = blockIdx.x * 4 + widx;
    if (w >= M / 16) return;
    int m = lane & 15, quad = lane >> 4;
    unsigned short* zt = &z[widx][0];
    int r0 = w * 16;

    short8 am[4], ar[4];
    #pragma unroll
    for (int ks = 0; ks < 4; ks++) {
        am[ks] = *(const short8*)(mean + (size_t)(r0 + m) * 128 + ks * 32 + quad * 8);
        ar[ks] = *(const short8*)(h1   + (size_t)(r0 + m) * 128 + ks * 32 + quad * 8);
    }

    // SAGE layer: h2 -> LDS (bf16) + value-head partials from C-layout
    float vpart[4] = {0.f, 0.f, 0.f, 0.f};
    #pragma unroll
    for (int ct = 0; ct < 8; ct++) {
        floatx4 acc = {0.f, 0.f, 0.f, 0.f};
        #pragma unroll
        for (int ks = 0; ks < 4; ks++) acc = MFMA(am[ks], FRAG(Psl, ct, ks, lane), acc);
        #pragma unroll
        for (int ks = 0; ks < 4; ks++) acc = MFMA(ar[ks], FRAG(Psr, ct, ks, lane), acc);
        float bb = bsl[ct * 16 + m];
        float wv = Wv[ct * 16 + m];
        #pragma unroll
        for (int reg = 0; reg < 4; reg++) {
            float o = fmaxf(acc[reg] + bb, 0.f);
            vpart[reg] = fmaf(o, wv, vpart[reg]);
            zt[(quad * 4 + reg) * 136 + ct * 16 + m] = f2b(o);
        }
    }
    // value: reduce across m-lanes within each quad
    #pragma unroll
    for (int off = 1; off <= 8; off <<= 1) {
        #pragma unroll
        for (int reg = 0; reg < 4; reg++)
            vpart[reg] += __shfl_xor(vpart[reg], off);
    }
    if (m == 0) {
        float bvv = bv[0];
        #pragma unroll
        for (int reg = 0; reg < 4; reg++)
            values[r0 + quad * 4 + reg] = vpart[reg] + bvv;
    }

    short8 a1[4];
    #pragma unroll
    for (int ks = 0; ks < 4; ks++)
        a1[ks] = *(const short8*)(zt + m * 136 + ks * 32 + quad * 8);

    // layer 1: gelu(h2 @ W1 + b1) -> LDS
    #pragma unroll
    for (int ct = 0; ct < 8; ct++) {
        floatx4 acc = {0.f, 0.f, 0.f, 0.f};
        #pragma unroll
        for (int ks = 0; ks < 4; ks++) acc = MFMA(a1[ks], FRAG(P1, ct, ks, lane), acc);
        float bb = b1[ct * 16 + m];
        #pragma unroll
        for (int reg = 0; reg < 4; reg++)
            zt[(quad * 4 + reg) * 136 + ct * 16 + m] = f2b(gelu_exact(acc[reg] + bb));
    }
    short8 a2[4];
    #pragma unroll
    for (int ks = 0; ks < 4; ks++)
        a2[ks] = *(const short8*)(zt + m * 136 + ks * 32 + quad * 8);

    // layer 2: gelu(z1 @ W2 + b2) -> LDS
    #pragma unroll
    for (int ct = 0; ct < 8; ct++) {
        floatx4 acc = {0.f, 0.f, 0.f, 0.f};
        #pragma unroll
        for (int ks = 0; ks < 4; ks++) acc = MFMA(a2[ks], FRAG(P2, ct, ks, lane), acc);
        float bb = b2[ct * 16 + m];
        #pragma unroll
        for (int reg = 0; reg < 4; reg++)
            zt[(quad * 4 + reg) * 136 + ct * 16 + m] = f2b(gelu_exact(acc[reg] + bb));
    }
    short8 a3[4];
    #pragma unroll
    for (int ks = 0; ks < 4; ks++)
        a3[ks] = *(const short8*)(zt + m * 136 + ks * 32 + quad * 8);

    // layer 3: means = z2 @ W3 + b3  (64 cols)
    #pragma unroll
    for (int ct = 0; ct < 4; ct++) {
        floatx4 acc = {0.f, 0.f, 0.f, 0.f};
        #pragma unroll
        for (int ks = 0; ks < 4; ks++) acc = MFMA(a3[ks], FRAG(P3, ct, ks, lane), acc);
        float bb = b3[ct * 16 + m];
        #pragma unroll
        for (int reg = 0; reg < 4; reg++)
            means[(size_t)(r0 + quad * 4 + reg) * 64 + ct * 16 + m] = acc[reg] + bb;
    }
}

// ---------------- launch ----------------

extern "C" void kernel_launch(void* const* d_in, const int* in_sizes, int n_in,
                              void* d_out, int out_size, void* d_ws, size_t ws_size,
                              hipStream_t stream) {
    const float* feat  = (const float*)d_in[0];
    const int*   eidx  = (const int*)d_in[1];
    const float* W_gcn = (const float*)d_in[2];
    const float* b_gcn = (const float*)d_in[3];
    const float* W_sl  = (const float*)d_in[4];
    const float* b_sl  = (const float*)d_in[5];
    const float* W_sr  = (const float*)d_in[6];
    const float* W1    = (const float*)d_in[7];
    const float* b1    = (const float*)d_in[8];
    const float* W2    = (const float*)d_in[9];
    const float* b2    = (const float*)d_in[10];
    const float* W3    = (const float*)d_in[11];
    const float* b3    = (const float*)d_in[12];
    const float* Wv    = (const float*)d_in[13];
    const float* bv    = (const float*)d_in[14];

    const int N = in_sizes[0] / 128;
    const int E = in_sizes[1] / 2;

    char* ws = (char*)d_ws;
    size_t off = 0;
    auto alloc = [&](size_t bytes) -> void* {
        void* p = ws + off;
        off += (bytes + 255) & ~(size_t)255;
        return p;
    };
    int*   cnt     = (int*)alloc((size_t)N * 4);
    int*   row_ptr = (int*)alloc((size_t)(N + 1) * 4);
    int*   cursor  = (int*)alloc((size_t)N * 4);
    float* dinv    = (float*)alloc((size_t)N * 4);
    int*   col     = (int*)alloc((size_t)E * 4);
    unsigned short* xs   = (unsigned short*)alloc((size_t)N * 128 * 2);
    unsigned short* h1   = (unsigned short*)alloc((size_t)N * 128 * 2);
    unsigned short* mean = (unsigned short*)alloc((size_t)N * 128 * 2);
    unsigned short* Pg   = (unsigned short*)alloc(2048 * 8 * 2);
    unsigned short* Psl  = (unsigned short*)alloc(2048 * 8 * 2);
    unsigned short* Psr  = (unsigned short*)alloc(2048 * 8 * 2);
    unsigned short* P1   = (unsigned short*)alloc(2048 * 8 * 2);
    unsigned short* P2   = (unsigned short*)alloc(2048 * 8 * 2);
    unsigned short* P3   = (unsigned short*)alloc(1024 * 8 * 2);

    hipMemsetAsync(cnt, 0, (size_t)N * 4, stream);

    const int countBlocks = (E + 255) / 256;               // 2500
    const int packBlocks  = (11264 + 255) / 256;           // 44
    count_pack_kernel<<<countBlocks + packBlocks, 256, 0, stream>>>(
        eidx, E, cnt, W_gcn, W_sl, W_sr, W1, W2, W3,
        Pg, Psl, Psr, P1, P2, P3, countBlocks);

    scan_kernel<<<1, 256, 0, stream>>>(cnt, N, E, row_ptr, cursor, dinv);

    const int fillBlocks = (E + 255) / 256;                // 2500
    const int gemmBlocks = ((N / 16) * 2 + 3) / 4;         // 625
    fill_gemm_kernel<<<fillBlocks + gemmBlocks, 256, 0, stream>>>(
        eidx, E, cursor, col, feat, dinv, Pg, xs, N, fillBlocks);

    const int agrid = (N + 3) / 4;
    agg_kernel<true><<<agrid, 256, 0, stream>>>(xs, row_ptr, col, dinv, b_gcn, h1, N);
    agg_kernel<false><<<agrid, 256, 0, stream>>>(h1, row_ptr, col, dinv, nullptr, mean, N);

    sage_mlp_kernel<<<(N / 16 + 3) / 4, 256, 0, stream>>>(
        mean, h1, Psl, Psr, b_sl, P1, b1, P2, b2, P3, b3, Wv, bv,
        (float*)d_out, (float*)d_out + (size_t)N * 64, N);
}

// Round 4
// 233.074 us; speedup vs baseline: 1.7845x; 1.2468x over previous
//
#include <hip/hip_runtime.h>
#include <math.h>

// N = 20000, E = 640000, IN_DIM = HID = 128, OUT = 64
// Activations bf16 (ushort bits), accumulation fp32 via MFMA 16x16x32.

typedef __attribute__((ext_vector_type(8))) short short8;
typedef __attribute__((ext_vector_type(4))) float floatx4;

__device__ __forceinline__ unsigned short f2b(float f) {
    unsigned u = __float_as_uint(f);
    unsigned r = (u + 0x7fffu + ((u >> 16) & 1u)) >> 16;
    return (unsigned short)r;
}
__device__ __forceinline__ float b2f(unsigned short h) {
    return __uint_as_float(((unsigned)h) << 16);
}
__device__ __forceinline__ float b2f_lo(unsigned v) {
    return __uint_as_float(v << 16);
}
__device__ __forceinline__ float b2f_hi(unsigned v) {
    return __uint_as_float(v & 0xffff0000u);
}
__device__ __forceinline__ floatx4 MFMA(short8 a, short8 b, floatx4 c) {
    return __builtin_amdgcn_mfma_f32_16x16x32_bf16(a, b, c, 0, 0, 0);
}
__device__ __forceinline__ float gelu_exact(float x) {
    return 0.5f * x * (1.0f + erff(x * 0.70710678118654752440f));
}

// B fragment for (ct, ks) at lane: packed W layout
#define FRAG(P, ct, ks, lane) (*(const short8*)((P) + (((((ct)*4 + (ks))*64) + (lane)) << 3)))

// ---------------- count (fire-and-forget atomics) + weight packing ---------
// NO fences, NO done-counter: visibility to later dispatches comes from the
// implicit end-of-kernel release. (Round-1 lesson: per-block __threadfence
// costs an L2 writeback each -> +180us across 2544 blocks.)

__global__ __launch_bounds__(256) void count_pack_kernel(
    const int* __restrict__ eidx, int E,
    int* __restrict__ cnt,
    const float* Wg, const float* Wsl, const float* Wsr,
    const float* W1, const float* W2, const float* W3,
    unsigned short* Pg, unsigned short* Psl, unsigned short* Psr,
    unsigned short* P1, unsigned short* P2, unsigned short* P3,
    int countBlocks)
{
    if ((int)blockIdx.x < countBlocks) {
        int e = blockIdx.x * 256 + threadIdx.x;
        if (e < E) atomicAdd(&cnt[eidx[E + e]], 1);   // no return -> fire & forget
        return;
    }
    int t = (blockIdx.x - countBlocks) * 256 + threadIdx.x;
    const float* W; unsigned short* P; int NC = 128; int base;
    if (t < 2048)       { W = Wg;  P = Pg;  base = t; }
    else if (t < 4096)  { W = Wsl; P = Psl; base = t - 2048; }
    else if (t < 6144)  { W = Wsr; P = Psr; base = t - 4096; }
    else if (t < 8192)  { W = W1;  P = P1;  base = t - 6144; }
    else if (t < 10240) { W = W2;  P = P2;  base = t - 8192; }
    else if (t < 11264) { W = W3;  P = P3;  base = t - 10240; NC = 64; }
    else return;
    int l  = base & 63;
    int ks = (base >> 6) & 3;
    int ct = base >> 8;
    int n  = ct * 16 + (l & 15);
    int k0 = ks * 32 + ((l >> 4) << 3);
    short8 v;
    #pragma unroll
    for (int j = 0; j < 8; j++) v[j] = (short)f2b(W[(size_t)(k0 + j) * NC + n]);
    *(short8*)(P + ((size_t)base << 3)) = v;
}

// ---------------- communication-free parallel scan ----------------
// 20 blocks. Block b: (1) base = sum cnt[0 .. b*1024) via int4 stripe-sum +
// block reduce (redundant across blocks, ~0.8 MB total L2 reads -- cheap);
// (2) round-0-style local scan of its 1024 elements; emit GLOBAL row_ptr
// (row_ptr[N]=E), cursor copy, dinv = rsqrt(deg+1). No fences, no bsums.
// (Round-3 lesson: 1-block scan = 68us of bare latency, 0.04% occupancy.)

__global__ __launch_bounds__(256) void scan_kernel(
    const int* __restrict__ cnt, int N, int E,
    int* __restrict__ row_ptr, int* __restrict__ cursor, float* __restrict__ dinv,
    int NB)
{
    __shared__ int red[256];
    __shared__ int sh[256];
    int b = blockIdx.x, tid = threadIdx.x;

    // ---- phase 1: base = sum of cnt[0 .. b*1024) ----
    const int4* c4 = (const int4*)cnt;
    int nvec = b * 256;                    // int4 elements before this block
    int s = 0;
    for (int i = tid; i < nvec; i += 256) {
        int4 v = c4[i];
        s += v.x + v.y + v.z + v.w;
    }
    red[tid] = s;
    __syncthreads();
    #pragma unroll
    for (int off = 128; off > 0; off >>= 1) {
        if (tid < off) red[tid] += red[tid + off];
        __syncthreads();
    }
    int base = red[0];

    // ---- phase 2: local scan of this block's 1024 elements ----
    int i0 = b * 1024 + tid * 4;
    int v0 = (i0 + 0 < N) ? cnt[i0 + 0] : 0;
    int v1 = (i0 + 1 < N) ? cnt[i0 + 1] : 0;
    int v2 = (i0 + 2 < N) ? cnt[i0 + 2] : 0;
    int v3 = (i0 + 3 < N) ? cnt[i0 + 3] : 0;
    int tot = v0 + v1 + v2 + v3;
    sh[tid] = tot;
    __syncthreads();
    for (int off = 1; off < 256; off <<= 1) {
        int t = (tid >= off) ? sh[tid - off] : 0;
        __syncthreads();
        sh[tid] += t;
        __syncthreads();
    }
    int excl = base + sh[tid] - tot;
    if (i0 + 0 < N) { row_ptr[i0+0] = excl;                cursor[i0+0] = excl;                dinv[i0+0] = rsqrtf((float)(v0+1)); }
    if (i0 + 1 < N) { row_ptr[i0+1] = excl+v0;             cursor[i0+1] = excl+v0;             dinv[i0+1] = rsqrtf((float)(v1+1)); }
    if (i0 + 2 < N) { row_ptr[i0+2] = excl+v0+v1;          cursor[i0+2] = excl+v0+v1;          dinv[i0+2] = rsqrtf((float)(v2+1)); }
    if (i0 + 3 < N) { row_ptr[i0+3] = excl+v0+v1+v2;       cursor[i0+3] = excl+v0+v1+v2;       dinv[i0+3] = rsqrtf((float)(v3+1)); }
    if (b == NB - 1 && tid == 255) row_ptr[N] = E;
}

// ---------------- fill (cursor atomics) + GCN GEMM (dinv pre-folded) -------

__global__ __launch_bounds__(256) void fill_gemm_kernel(
    const int* __restrict__ eidx, int E,
    int* __restrict__ cursor, int* __restrict__ col,
    const float* __restrict__ feat, const float* __restrict__ dinv,
    const unsigned short* __restrict__ Pg,
    unsigned short* __restrict__ xs, int M, int fillBlocks)
{
    if ((int)blockIdx.x < fillBlocks) {
        int e = blockIdx.x * 256 + threadIdx.x;
        if (e < E) {
            int d = eidx[E + e];
            int pos = atomicAdd(&cursor[d], 1);
            col[pos] = eidx[e];
        }
        return;
    }
    // GCN GEMM: wave computes 16 rows x 64 cols of xs = bf16(dinv[row] * (feat @ Wg))
    int bid = blockIdx.x - fillBlocks;
    int w = bid * 4 + (threadIdx.x >> 6);
    if (w >= (M / 16) * 2) return;
    int lane = threadIdx.x & 63;
    int m = lane & 15, quad = lane >> 4;
    int rt = w >> 1, ch = w & 1;
    const float* arow = feat + (size_t)(rt * 16 + m) * 128;
    short8 a[4];
    #pragma unroll
    for (int ks = 0; ks < 4; ks++) {
        float4 f0 = *(const float4*)(arow + ks * 32 + quad * 8);
        float4 f1 = *(const float4*)(arow + ks * 32 + quad * 8 + 4);
        short8 s;
        s[0] = (short)f2b(f0.x); s[1] = (short)f2b(f0.y);
        s[2] = (short)f2b(f0.z); s[3] = (short)f2b(f0.w);
        s[4] = (short)f2b(f1.x); s[5] = (short)f2b(f1.y);
        s[6] = (short)f2b(f1.z); s[7] = (short)f2b(f1.w);
        a[ks] = s;
    }
    float4 dvv = *(const float4*)(dinv + rt * 16 + quad * 4);
    float dv[4] = {dvv.x, dvv.y, dvv.z, dvv.w};
    #pragma unroll
    for (int ct = 0; ct < 4; ct++) {
        floatx4 acc = {0.f, 0.f, 0.f, 0.f};
        #pragma unroll
        for (int ks = 0; ks < 4; ks++)
            acc = MFMA(a[ks], FRAG(Pg, ch * 4 + ct, ks, lane), acc);
        #pragma unroll
        for (int reg = 0; reg < 4; reg++)
            xs[(size_t)(rt * 16 + quad * 4 + reg) * 128 + (ch * 4 + ct) * 16 + m] =
                f2b(acc[reg] * dv[reg]);
    }
}

// ---------------- aggregation: 16 lanes per edge-row, direct col broadcast --
// GCN:  xs pre-scaled by dinv[s]; h1[d] = relu(dinv[d]*(sum_s xs[s] + xs[d]) + b)
// SAGE: mean[d] = (1/max(deg,1)) * sum_s h1[s]

template<bool GCN>
__global__ __launch_bounds__(256) void agg_kernel(
    const unsigned short* __restrict__ X, const int* __restrict__ row_ptr,
    const int* __restrict__ col, const float* __restrict__ dinv,
    const float* __restrict__ bias,
    unsigned short* __restrict__ Y, int N)
{
    int w = (int)((blockIdx.x * 256 + threadIdx.x) >> 6);
    if (w >= N) return;
    int lane = threadIdx.x & 63;
    int g = lane >> 4, t = lane & 15;
    const uint4* Xq = (const uint4*)X;

    int beg = row_ptr[w], end = row_ptr[w + 1];
    int deg = end - beg;

    float acc[8] = {0.f, 0.f, 0.f, 0.f, 0.f, 0.f, 0.f, 0.f};

    int e = beg + g;
    for (; e + 4 < end; e += 8) {
        int s0 = col[e];
        int s1 = col[e + 4];
        uint4 q0 = Xq[(size_t)s0 * 16 + t];
        uint4 q1 = Xq[(size_t)s1 * 16 + t];
        acc[0] += b2f_lo(q0.x); acc[1] += b2f_hi(q0.x);
        acc[2] += b2f_lo(q0.y); acc[3] += b2f_hi(q0.y);
        acc[4] += b2f_lo(q0.z); acc[5] += b2f_hi(q0.z);
        acc[6] += b2f_lo(q0.w); acc[7] += b2f_hi(q0.w);
        acc[0] += b2f_lo(q1.x); acc[1] += b2f_hi(q1.x);
        acc[2] += b2f_lo(q1.y); acc[3] += b2f_hi(q1.y);
        acc[4] += b2f_lo(q1.z); acc[5] += b2f_hi(q1.z);
        acc[6] += b2f_lo(q1.w); acc[7] += b2f_hi(q1.w);
    }
    if (e < end) {
        int s0 = col[e];
        uint4 q0 = Xq[(size_t)s0 * 16 + t];
        acc[0] += b2f_lo(q0.x); acc[1] += b2f_hi(q0.x);
        acc[2] += b2f_lo(q0.y); acc[3] += b2f_hi(q0.y);
        acc[4] += b2f_lo(q0.z); acc[5] += b2f_hi(q0.z);
        acc[6] += b2f_lo(q0.w); acc[7] += b2f_hi(q0.w);
    }

    // reduce across the 4 groups
    #pragma unroll
    for (int i = 0; i < 8; i++) {
        acc[i] += __shfl_xor(acc[i], 16);
        acc[i] += __shfl_xor(acc[i], 32);
    }
    if (g == 0) {
        float out[8];
        if (GCN) {
            float dw = dinv[w];
            uint4 q = Xq[(size_t)w * 16 + t];  // self loop (pre-scaled by dinv[w])
            acc[0] += b2f_lo(q.x); acc[1] += b2f_hi(q.x);
            acc[2] += b2f_lo(q.y); acc[3] += b2f_hi(q.y);
            acc[4] += b2f_lo(q.z); acc[5] += b2f_hi(q.z);
            acc[6] += b2f_lo(q.w); acc[7] += b2f_hi(q.w);
            float4 b0 = *(const float4*)(bias + t * 8);
            float4 b1 = *(const float4*)(bias + t * 8 + 4);
            out[0] = fmaxf(fmaf(acc[0], dw, b0.x), 0.f);
            out[1] = fmaxf(fmaf(acc[1], dw, b0.y), 0.f);
            out[2] = fmaxf(fmaf(acc[2], dw, b0.z), 0.f);
            out[3] = fmaxf(fmaf(acc[3], dw, b0.w), 0.f);
            out[4] = fmaxf(fmaf(acc[4], dw, b1.x), 0.f);
            out[5] = fmaxf(fmaf(acc[5], dw, b1.y), 0.f);
            out[6] = fmaxf(fmaf(acc[6], dw, b1.z), 0.f);
            out[7] = fmaxf(fmaf(acc[7], dw, b1.w), 0.f);
        } else {
            float rc = 1.0f / (float)(deg > 0 ? deg : 1);
            #pragma unroll
            for (int i = 0; i < 8; i++) out[i] = acc[i] * rc;
        }
        uint4 r;
        r.x = (unsigned)f2b(out[0]) | ((unsigned)f2b(out[1]) << 16);
        r.y = (unsigned)f2b(out[2]) | ((unsigned)f2b(out[3]) << 16);
        r.z = (unsigned)f2b(out[4]) | ((unsigned)f2b(out[5]) << 16);
        r.w = (unsigned)f2b(out[6]) | ((unsigned)f2b(out[7]) << 16);
        ((uint4*)Y)[(size_t)w * 16 + t] = r;
    }
}

// ---------------- fused SAGE + policy MLP + value head ----------------
// Per wave: 16 rows. h2 = relu(mean@Wsl + h1@Wsr + bsl) stays in LDS;
// then gelu(W1), gelu(W2), W3 -> means; value = h2@Wv+bv from C-layout.

__global__ __launch_bounds__(256) void sage_mlp_kernel(
    const unsigned short* __restrict__ mean, const unsigned short* __restrict__ h1,
    const unsigned short* __restrict__ Psl, const unsigned short* __restrict__ Psr,
    const float* __restrict__ bsl,
    const unsigned short* __restrict__ P1, const float* __restrict__ b1,
    const unsigned short* __restrict__ P2, const float* __restrict__ b2,
    const unsigned short* __restrict__ P3, const float* __restrict__ b3,
    const float* __restrict__ Wv, const float* __restrict__ bv,
    float* __restrict__ means, float* __restrict__ values, int M)
{
    __shared__ unsigned short z[4][16 * 136];
    int widx = threadIdx.x >> 6, lane = threadIdx.x & 63;
    int w = blockIdx.x * 4 + widx;
    if (w >= M / 16) return;
    int m = lane & 15, quad = lane >> 4;
    unsigned short* zt = &z[widx][0];
    int r0 = w * 16;

    short8 am[4], ar[4];
    #pragma unroll
    for (int ks = 0; ks < 4; ks++) {
        am[ks] = *(const short8*)(mean + (size_t)(r0 + m) * 128 + ks * 32 + quad * 8);
        ar[ks] = *(const short8*)(h1   + (size_t)(r0 + m) * 128 + ks * 32 + quad * 8);
    }

    // SAGE layer: h2 -> LDS (bf16) + value-head partials from C-layout
    float vpart[4] = {0.f, 0.f, 0.f, 0.f};
    #pragma unroll
    for (int ct = 0; ct < 8; ct++) {
        floatx4 acc = {0.f, 0.f, 0.f, 0.f};
        #pragma unroll
        for (int ks = 0; ks < 4; ks++) acc = MFMA(am[ks], FRAG(Psl, ct, ks, lane), acc);
        #pragma unroll
        for (int ks = 0; ks < 4; ks++) acc = MFMA(ar[ks], FRAG(Psr, ct, ks, lane), acc);
        float bb = bsl[ct * 16 + m];
        float wv = Wv[ct * 16 + m];
        #pragma unroll
        for (int reg = 0; reg < 4; reg++) {
            float o = fmaxf(acc[reg] + bb, 0.f);
            vpart[reg] = fmaf(o, wv, vpart[reg]);
            zt[(quad * 4 + reg) * 136 + ct * 16 + m] = f2b(o);
        }
    }
    // value: reduce across m-lanes within each quad
    #pragma unroll
    for (int off = 1; off <= 8; off <<= 1) {
        #pragma unroll
        for (int reg = 0; reg < 4; reg++)
            vpart[reg] += __shfl_xor(vpart[reg], off);
    }
    if (m == 0) {
        float bvv = bv[0];
        #pragma unroll
        for (int reg = 0; reg < 4; reg++)
            values[r0 + quad * 4 + reg] = vpart[reg] + bvv;
    }

    short8 a1[4];
    #pragma unroll
    for (int ks = 0; ks < 4; ks++)
        a1[ks] = *(const short8*)(zt + m * 136 + ks * 32 + quad * 8);

    // layer 1: gelu(h2 @ W1 + b1) -> LDS
    #pragma unroll
    for (int ct = 0; ct < 8; ct++) {
        floatx4 acc = {0.f, 0.f, 0.f, 0.f};
        #pragma unroll
        for (int ks = 0; ks < 4; ks++) acc = MFMA(a1[ks], FRAG(P1, ct, ks, lane), acc);
        float bb = b1[ct * 16 + m];
        #pragma unroll
        for (int reg = 0; reg < 4; reg++)
            zt[(quad * 4 + reg) * 136 + ct * 16 + m] = f2b(gelu_exact(acc[reg] + bb));
    }
    short8 a2[4];
    #pragma unroll
    for (int ks = 0; ks < 4; ks++)
        a2[ks] = *(const short8*)(zt + m * 136 + ks * 32 + quad * 8);

    // layer 2: gelu(z1 @ W2 + b2) -> LDS
    #pragma unroll
    for (int ct = 0; ct < 8; ct++) {
        floatx4 acc = {0.f, 0.f, 0.f, 0.f};
        #pragma unroll
        for (int ks = 0; ks < 4; ks++) acc = MFMA(a2[ks], FRAG(P2, ct, ks, lane), acc);
        float bb = b2[ct * 16 + m];
        #pragma unroll
        for (int reg = 0; reg < 4; reg++)
            zt[(quad * 4 + reg) * 136 + ct * 16 + m] = f2b(gelu_exact(acc[reg] + bb));
    }
    short8 a3[4];
    #pragma unroll
    for (int ks = 0; ks < 4; ks++)
        a3[ks] = *(const short8*)(zt + m * 136 + ks * 32 + quad * 8);

    // layer 3: means = z2 @ W3 + b3  (64 cols)
    #pragma unroll
    for (int ct = 0; ct < 4; ct++) {
        floatx4 acc = {0.f, 0.f, 0.f, 0.f};
        #pragma unroll
        for (int ks = 0; ks < 4; ks++) acc = MFMA(a3[ks], FRAG(P3, ct, ks, lane), acc);
        float bb = b3[ct * 16 + m];
        #pragma unroll
        for (int reg = 0; reg < 4; reg++)
            means[(size_t)(r0 + quad * 4 + reg) * 64 + ct * 16 + m] = acc[reg] + bb;
    }
}

// ---------------- launch ----------------

extern "C" void kernel_launch(void* const* d_in, const int* in_sizes, int n_in,
                              void* d_out, int out_size, void* d_ws, size_t ws_size,
                              hipStream_t stream) {
    const float* feat  = (const float*)d_in[0];
    const int*   eidx  = (const int*)d_in[1];
    const float* W_gcn = (const float*)d_in[2];
    const float* b_gcn = (const float*)d_in[3];
    const float* W_sl  = (const float*)d_in[4];
    const float* b_sl  = (const float*)d_in[5];
    const float* W_sr  = (const float*)d_in[6];
    const float* W1    = (const float*)d_in[7];
    const float* b1    = (const float*)d_in[8];
    const float* W2    = (const float*)d_in[9];
    const float* b2    = (const float*)d_in[10];
    const float* W3    = (const float*)d_in[11];
    const float* b3    = (const float*)d_in[12];
    const float* Wv    = (const float*)d_in[13];
    const float* bv    = (const float*)d_in[14];

    const int N = in_sizes[0] / 128;
    const int E = in_sizes[1] / 2;

    char* ws = (char*)d_ws;
    size_t off = 0;
    auto alloc = [&](size_t bytes) -> void* {
        void* p = ws + off;
        off += (bytes + 255) & ~(size_t)255;
        return p;
    };
    int*   cnt     = (int*)alloc((size_t)N * 4);
    int*   row_ptr = (int*)alloc((size_t)(N + 1) * 4);
    int*   cursor  = (int*)alloc((size_t)N * 4);
    float* dinv    = (float*)alloc((size_t)N * 4);
    int*   col     = (int*)alloc((size_t)E * 4);
    unsigned short* xs   = (unsigned short*)alloc((size_t)N * 128 * 2);
    unsigned short* h1   = (unsigned short*)alloc((size_t)N * 128 * 2);
    unsigned short* mean = (unsigned short*)alloc((size_t)N * 128 * 2);
    unsigned short* Pg   = (unsigned short*)alloc(2048 * 8 * 2);
    unsigned short* Psl  = (unsigned short*)alloc(2048 * 8 * 2);
    unsigned short* Psr  = (unsigned short*)alloc(2048 * 8 * 2);
    unsigned short* P1   = (unsigned short*)alloc(2048 * 8 * 2);
    unsigned short* P2   = (unsigned short*)alloc(2048 * 8 * 2);
    unsigned short* P3   = (unsigned short*)alloc(1024 * 8 * 2);

    hipMemsetAsync(cnt, 0, (size_t)N * 4, stream);

    const int countBlocks = (E + 255) / 256;               // 2500
    const int packBlocks  = (11264 + 255) / 256;           // 44
    count_pack_kernel<<<countBlocks + packBlocks, 256, 0, stream>>>(
        eidx, E, cnt, W_gcn, W_sl, W_sr, W1, W2, W3,
        Pg, Psl, Psr, P1, P2, P3, countBlocks);

    const int NB = (N + 1023) / 1024;                      // 20
    scan_kernel<<<NB, 256, 0, stream>>>(cnt, N, E, row_ptr, cursor, dinv, NB);

    const int fillBlocks = (E + 255) / 256;                // 2500
    const int gemmBlocks = ((N / 16) * 2 + 3) / 4;         // 625
    fill_gemm_kernel<<<fillBlocks + gemmBlocks, 256, 0, stream>>>(
        eidx, E, cursor, col, feat, dinv, Pg, xs, N, fillBlocks);

    const int agrid = (N + 3) / 4;
    agg_kernel<true><<<agrid, 256, 0, stream>>>(xs, row_ptr, col, dinv, b_gcn, h1, N);
    agg_kernel<false><<<agrid, 256, 0, stream>>>(h1, row_ptr, col, dinv, nullptr, mean, N);

    sage_mlp_kernel<<<(N / 16 + 3) / 4, 256, 0, stream>>>(
        mean, h1, Psl, Psr, b_sl, P1, b1, P2, b2, P3, b3, Wv, bv,
        (float*)d_out, (float*)d_out + (size_t)N * 64, N);
}

// Round 5
// 221.330 us; speedup vs baseline: 1.8792x; 1.0531x over previous
//
#include <hip/hip_runtime.h>
#include <math.h>

// N = 20000, E = 640000, IN_DIM = HID = 128, OUT = 64
// Activations bf16 (ushort bits), accumulation fp32 via MFMA 16x16x32.

typedef __attribute__((ext_vector_type(8))) short short8;
typedef __attribute__((ext_vector_type(4))) float floatx4;

__device__ __forceinline__ unsigned short f2b(float f) {
    unsigned u = __float_as_uint(f);
    unsigned r = (u + 0x7fffu + ((u >> 16) & 1u)) >> 16;
    return (unsigned short)r;
}
__device__ __forceinline__ float b2f(unsigned short h) {
    return __uint_as_float(((unsigned)h) << 16);
}
__device__ __forceinline__ float b2f_lo(unsigned v) {
    return __uint_as_float(v << 16);
}
__device__ __forceinline__ float b2f_hi(unsigned v) {
    return __uint_as_float(v & 0xffff0000u);
}
__device__ __forceinline__ floatx4 MFMA(short8 a, short8 b, floatx4 c) {
    return __builtin_amdgcn_mfma_f32_16x16x32_bf16(a, b, c, 0, 0, 0);
}
__device__ __forceinline__ float gelu_exact(float x) {
    return 0.5f * x * (1.0f + erff(x * 0.70710678118654752440f));
}

// B fragment for (ct, ks) at lane: packed W layout
#define FRAG(P, ct, ks, lane) (*(const short8*)((P) + (((((ct)*4 + (ks))*64) + (lane)) << 3)))

// ---------------- count (fire-and-forget atomics) + weight packing ---------
// NO fences, NO done-counter: visibility to later dispatches comes from the
// implicit end-of-kernel release. (Round-1 lesson: per-block __threadfence
// costs an L2 writeback each -> +180us across 2544 blocks.)

__global__ __launch_bounds__(256) void count_pack_kernel(
    const int* __restrict__ eidx, int E,
    int* __restrict__ cnt,
    const float* Wg, const float* Wsl, const float* Wsr,
    const float* W1, const float* W2, const float* W3,
    unsigned short* Pg, unsigned short* Psl, unsigned short* Psr,
    unsigned short* P1, unsigned short* P2, unsigned short* P3,
    int countBlocks)
{
    if ((int)blockIdx.x < countBlocks) {
        int e = blockIdx.x * 256 + threadIdx.x;
        if (e < E) atomicAdd(&cnt[eidx[E + e]], 1);   // no return -> fire & forget
        return;
    }
    int t = (blockIdx.x - countBlocks) * 256 + threadIdx.x;
    const float* W; unsigned short* P; int NC = 128; int base;
    if (t < 2048)       { W = Wg;  P = Pg;  base = t; }
    else if (t < 4096)  { W = Wsl; P = Psl; base = t - 2048; }
    else if (t < 6144)  { W = Wsr; P = Psr; base = t - 4096; }
    else if (t < 8192)  { W = W1;  P = P1;  base = t - 6144; }
    else if (t < 10240) { W = W2;  P = P2;  base = t - 8192; }
    else if (t < 11264) { W = W3;  P = P3;  base = t - 10240; NC = 64; }
    else return;
    int l  = base & 63;
    int ks = (base >> 6) & 3;
    int ct = base >> 8;
    int n  = ct * 16 + (l & 15);
    int k0 = ks * 32 + ((l >> 4) << 3);
    short8 v;
    #pragma unroll
    for (int j = 0; j < 8; j++) v[j] = (short)f2b(W[(size_t)(k0 + j) * NC + n]);
    *(short8*)(P + ((size_t)base << 3)) = v;
}

// ---------------- communication-free parallel scan ----------------
// 20 blocks. Block b: (1) base = sum cnt[0 .. b*1024) via int4 stripe-sum +
// block reduce (redundant across blocks, ~0.8 MB total L2 reads -- cheap);
// (2) local scan of its 1024 elements; emit GLOBAL row_ptr (row_ptr[N]=E),
// cursor copy, dinv = rsqrt(deg+1). No fences, no bsums.
// (Round-3 lesson: 1-block scan = 68us of bare latency, 0.04% occupancy.)

__global__ __launch_bounds__(256) void scan_kernel(
    const int* __restrict__ cnt, int N, int E,
    int* __restrict__ row_ptr, int* __restrict__ cursor, float* __restrict__ dinv,
    int NB)
{
    __shared__ int red[256];
    __shared__ int sh[256];
    int b = blockIdx.x, tid = threadIdx.x;

    // ---- phase 1: base = sum of cnt[0 .. b*1024) ----
    const int4* c4 = (const int4*)cnt;
    int nvec = b * 256;                    // int4 elements before this block
    int s = 0;
    for (int i = tid; i < nvec; i += 256) {
        int4 v = c4[i];
        s += v.x + v.y + v.z + v.w;
    }
    red[tid] = s;
    __syncthreads();
    #pragma unroll
    for (int off = 128; off > 0; off >>= 1) {
        if (tid < off) red[tid] += red[tid + off];
        __syncthreads();
    }
    int base = red[0];

    // ---- phase 2: local scan of this block's 1024 elements ----
    int i0 = b * 1024 + tid * 4;
    int v0 = (i0 + 0 < N) ? cnt[i0 + 0] : 0;
    int v1 = (i0 + 1 < N) ? cnt[i0 + 1] : 0;
    int v2 = (i0 + 2 < N) ? cnt[i0 + 2] : 0;
    int v3 = (i0 + 3 < N) ? cnt[i0 + 3] : 0;
    int tot = v0 + v1 + v2 + v3;
    sh[tid] = tot;
    __syncthreads();
    for (int off = 1; off < 256; off <<= 1) {
        int t = (tid >= off) ? sh[tid - off] : 0;
        __syncthreads();
        sh[tid] += t;
        __syncthreads();
    }
    int excl = base + sh[tid] - tot;
    if (i0 + 0 < N) { row_ptr[i0+0] = excl;                cursor[i0+0] = excl;                dinv[i0+0] = rsqrtf((float)(v0+1)); }
    if (i0 + 1 < N) { row_ptr[i0+1] = excl+v0;             cursor[i0+1] = excl+v0;             dinv[i0+1] = rsqrtf((float)(v1+1)); }
    if (i0 + 2 < N) { row_ptr[i0+2] = excl+v0+v1;          cursor[i0+2] = excl+v0+v1;          dinv[i0+2] = rsqrtf((float)(v2+1)); }
    if (i0 + 3 < N) { row_ptr[i0+3] = excl+v0+v1+v2;       cursor[i0+3] = excl+v0+v1+v2;       dinv[i0+3] = rsqrtf((float)(v3+1)); }
    if (b == NB - 1 && tid == 255) row_ptr[N] = E;
}

// ---------------- fill (XCD-partitioned scatter) + GCN GEMM ----------------
// Round-4 lesson: all-XCD random 4B scatter into col -> every XCD's L2
// dirties nearly every 64B line of col -> ~8x writeback amplification
// (WRITE_SIZE 44.7 MB vs 7.7 MB ideal). Fix: block b = (chunk b>>3,
// partition b&7); blockIdx%8 lands on XCD b%8 (heuristic -- correctness
// never depends on it), so each col/cursor line has ONE L2 owner.
// Cost: dst chunk re-read x8, IC-resident (~few us).

__global__ __launch_bounds__(256) void fill_gemm_kernel(
    const int* __restrict__ eidx, int E, int N,
    int* __restrict__ cursor, int* __restrict__ col,
    const float* __restrict__ feat, const float* __restrict__ dinv,
    const unsigned short* __restrict__ Pg,
    unsigned short* __restrict__ xs, int M, int fillBlocks, int PS)
{
    if ((int)blockIdx.x < fillBlocks) {
        int chunk = blockIdx.x >> 3;
        int p = blockIdx.x & 7;
        int lo = p * PS;
        int hi = lo + PS;
        int e0 = chunk * 2048;
        int e1 = e0 + 2048 < E ? e0 + 2048 : E;
        for (int e = e0 + (int)threadIdx.x; e < e1; e += 256) {
            int d = eidx[E + e];
            if (d >= lo && d < hi) {
                int pos = atomicAdd(&cursor[d], 1);
                col[pos] = eidx[e];
            }
        }
        return;
    }
    // GCN GEMM: wave computes 16 rows x 64 cols of xs = bf16(dinv[row] * (feat @ Wg))
    int bid = blockIdx.x - fillBlocks;
    int w = bid * 4 + (threadIdx.x >> 6);
    if (w >= (M / 16) * 2) return;
    int lane = threadIdx.x & 63;
    int m = lane & 15, quad = lane >> 4;
    int rt = w >> 1, ch = w & 1;
    const float* arow = feat + (size_t)(rt * 16 + m) * 128;
    short8 a[4];
    #pragma unroll
    for (int ks = 0; ks < 4; ks++) {
        float4 f0 = *(const float4*)(arow + ks * 32 + quad * 8);
        float4 f1 = *(const float4*)(arow + ks * 32 + quad * 8 + 4);
        short8 s;
        s[0] = (short)f2b(f0.x); s[1] = (short)f2b(f0.y);
        s[2] = (short)f2b(f0.z); s[3] = (short)f2b(f0.w);
        s[4] = (short)f2b(f1.x); s[5] = (short)f2b(f1.y);
        s[6] = (short)f2b(f1.z); s[7] = (short)f2b(f1.w);
        a[ks] = s;
    }
    float4 dvv = *(const float4*)(dinv + rt * 16 + quad * 4);
    float dv[4] = {dvv.x, dvv.y, dvv.z, dvv.w};
    #pragma unroll
    for (int ct = 0; ct < 4; ct++) {
        floatx4 acc = {0.f, 0.f, 0.f, 0.f};
        #pragma unroll
        for (int ks = 0; ks < 4; ks++)
            acc = MFMA(a[ks], FRAG(Pg, ch * 4 + ct, ks, lane), acc);
        #pragma unroll
        for (int reg = 0; reg < 4; reg++)
            xs[(size_t)(rt * 16 + quad * 4 + reg) * 128 + (ch * 4 + ct) * 16 + m] =
                f2b(acc[reg] * dv[reg]);
    }
}

// ---------------- aggregation: 16 lanes per edge-row, direct col broadcast --
// GCN:  xs pre-scaled by dinv[s]; h1[d] = relu(dinv[d]*(sum_s xs[s] + xs[d]) + b)
// SAGE: mean[d] = (1/max(deg,1)) * sum_s h1[s]

template<bool GCN>
__global__ __launch_bounds__(256) void agg_kernel(
    const unsigned short* __restrict__ X, const int* __restrict__ row_ptr,
    const int* __restrict__ col, const float* __restrict__ dinv,
    const float* __restrict__ bias,
    unsigned short* __restrict__ Y, int N)
{
    int w = (int)((blockIdx.x * 256 + threadIdx.x) >> 6);
    if (w >= N) return;
    int lane = threadIdx.x & 63;
    int g = lane >> 4, t = lane & 15;
    const uint4* Xq = (const uint4*)X;

    int beg = row_ptr[w], end = row_ptr[w + 1];
    int deg = end - beg;

    float acc[8] = {0.f, 0.f, 0.f, 0.f, 0.f, 0.f, 0.f, 0.f};

    int e = beg + g;
    for (; e + 4 < end; e += 8) {
        int s0 = col[e];
        int s1 = col[e + 4];
        uint4 q0 = Xq[(size_t)s0 * 16 + t];
        uint4 q1 = Xq[(size_t)s1 * 16 + t];
        acc[0] += b2f_lo(q0.x); acc[1] += b2f_hi(q0.x);
        acc[2] += b2f_lo(q0.y); acc[3] += b2f_hi(q0.y);
        acc[4] += b2f_lo(q0.z); acc[5] += b2f_hi(q0.z);
        acc[6] += b2f_lo(q0.w); acc[7] += b2f_hi(q0.w);
        acc[0] += b2f_lo(q1.x); acc[1] += b2f_hi(q1.x);
        acc[2] += b2f_lo(q1.y); acc[3] += b2f_hi(q1.y);
        acc[4] += b2f_lo(q1.z); acc[5] += b2f_hi(q1.z);
        acc[6] += b2f_lo(q1.w); acc[7] += b2f_hi(q1.w);
    }
    if (e < end) {
        int s0 = col[e];
        uint4 q0 = Xq[(size_t)s0 * 16 + t];
        acc[0] += b2f_lo(q0.x); acc[1] += b2f_hi(q0.x);
        acc[2] += b2f_lo(q0.y); acc[3] += b2f_hi(q0.y);
        acc[4] += b2f_lo(q0.z); acc[5] += b2f_hi(q0.z);
        acc[6] += b2f_lo(q0.w); acc[7] += b2f_hi(q0.w);
    }

    // reduce across the 4 groups
    #pragma unroll
    for (int i = 0; i < 8; i++) {
        acc[i] += __shfl_xor(acc[i], 16);
        acc[i] += __shfl_xor(acc[i], 32);
    }
    if (g == 0) {
        float out[8];
        if (GCN) {
            float dw = dinv[w];
            uint4 q = Xq[(size_t)w * 16 + t];  // self loop (pre-scaled by dinv[w])
            acc[0] += b2f_lo(q.x); acc[1] += b2f_hi(q.x);
            acc[2] += b2f_lo(q.y); acc[3] += b2f_hi(q.y);
            acc[4] += b2f_lo(q.z); acc[5] += b2f_hi(q.z);
            acc[6] += b2f_lo(q.w); acc[7] += b2f_hi(q.w);
            float4 b0 = *(const float4*)(bias + t * 8);
            float4 b1 = *(const float4*)(bias + t * 8 + 4);
            out[0] = fmaxf(fmaf(acc[0], dw, b0.x), 0.f);
            out[1] = fmaxf(fmaf(acc[1], dw, b0.y), 0.f);
            out[2] = fmaxf(fmaf(acc[2], dw, b0.z), 0.f);
            out[3] = fmaxf(fmaf(acc[3], dw, b0.w), 0.f);
            out[4] = fmaxf(fmaf(acc[4], dw, b1.x), 0.f);
            out[5] = fmaxf(fmaf(acc[5], dw, b1.y), 0.f);
            out[6] = fmaxf(fmaf(acc[6], dw, b1.z), 0.f);
            out[7] = fmaxf(fmaf(acc[7], dw, b1.w), 0.f);
        } else {
            float rc = 1.0f / (float)(deg > 0 ? deg : 1);
            #pragma unroll
            for (int i = 0; i < 8; i++) out[i] = acc[i] * rc;
        }
        uint4 r;
        r.x = (unsigned)f2b(out[0]) | ((unsigned)f2b(out[1]) << 16);
        r.y = (unsigned)f2b(out[2]) | ((unsigned)f2b(out[3]) << 16);
        r.z = (unsigned)f2b(out[4]) | ((unsigned)f2b(out[5]) << 16);
        r.w = (unsigned)f2b(out[6]) | ((unsigned)f2b(out[7]) << 16);
        ((uint4*)Y)[(size_t)w * 16 + t] = r;
    }
}

// ---------------- fused SAGE + policy MLP + value head ----------------
// Per wave: 16 rows. h2 = relu(mean@Wsl + h1@Wsr + bsl) stays in LDS;
// then gelu(W1), gelu(W2), W3 -> means; value = h2@Wv+bv from C-layout.

__global__ __launch_bounds__(256) void sage_mlp_kernel(
    const unsigned short* __restrict__ mean, const unsigned short* __restrict__ h1,
    const unsigned short* __restrict__ Psl, const unsigned short* __restrict__ Psr,
    const float* __restrict__ bsl,
    const unsigned short* __restrict__ P1, const float* __restrict__ b1,
    const unsigned short* __restrict__ P2, const float* __restrict__ b2,
    const unsigned short* __restrict__ P3, const float* __restrict__ b3,
    const float* __restrict__ Wv, const float* __restrict__ bv,
    float* __restrict__ means, float* __restrict__ values, int M)
{
    __shared__ unsigned short z[4][16 * 136];
    int widx = threadIdx.x >> 6, lane = threadIdx.x & 63;
    int w = blockIdx.x * 4 + widx;
    if (w >= M / 16) return;
    int m = lane & 15, quad = lane >> 4;
    unsigned short* zt = &z[widx][0];
    int r0 = w * 16;

    short8 am[4], ar[4];
    #pragma unroll
    for (int ks = 0; ks < 4; ks++) {
        am[ks] = *(const short8*)(mean + (size_t)(r0 + m) * 128 + ks * 32 + quad * 8);
        ar[ks] = *(const short8*)(h1   + (size_t)(r0 + m) * 128 + ks * 32 + quad * 8);
    }

    // SAGE layer: h2 -> LDS (bf16) + value-head partials from C-layout
    float vpart[4] = {0.f, 0.f, 0.f, 0.f};
    #pragma unroll
    for (int ct = 0; ct < 8; ct++) {
        floatx4 acc = {0.f, 0.f, 0.f, 0.f};
        #pragma unroll
        for (int ks = 0; ks < 4; ks++) acc = MFMA(am[ks], FRAG(Psl, ct, ks, lane), acc);
        #pragma unroll
        for (int ks = 0; ks < 4; ks++) acc = MFMA(ar[ks], FRAG(Psr, ct, ks, lane), acc);
        float bb = bsl[ct * 16 + m];
        float wv = Wv[ct * 16 + m];
        #pragma unroll
        for (int reg = 0; reg < 4; reg++) {
            float o = fmaxf(acc[reg] + bb, 0.f);
            vpart[reg] = fmaf(o, wv, vpart[reg]);
            zt[(quad * 4 + reg) * 136 + ct * 16 + m] = f2b(o);
        }
    }
    // value: reduce across m-lanes within each quad
    #pragma unroll
    for (int off = 1; off <= 8; off <<= 1) {
        #pragma unroll
        for (int reg = 0; reg < 4; reg++)
            vpart[reg] += __shfl_xor(vpart[reg], off);
    }
    if (m == 0) {
        float bvv = bv[0];
        #pragma unroll
        for (int reg = 0; reg < 4; reg++)
            values[r0 + quad * 4 + reg] = vpart[reg] + bvv;
    }

    short8 a1[4];
    #pragma unroll
    for (int ks = 0; ks < 4; ks++)
        a1[ks] = *(const short8*)(zt + m * 136 + ks * 32 + quad * 8);

    // layer 1: gelu(h2 @ W1 + b1) -> LDS
    #pragma unroll
    for (int ct = 0; ct < 8; ct++) {
        floatx4 acc = {0.f, 0.f, 0.f, 0.f};
        #pragma unroll
        for (int ks = 0; ks < 4; ks++) acc = MFMA(a1[ks], FRAG(P1, ct, ks, lane), acc);
        float bb = b1[ct * 16 + m];
        #pragma unroll
        for (int reg = 0; reg < 4; reg++)
            zt[(quad * 4 + reg) * 136 + ct * 16 + m] = f2b(gelu_exact(acc[reg] + bb));
    }
    short8 a2[4];
    #pragma unroll
    for (int ks = 0; ks < 4; ks++)
        a2[ks] = *(const short8*)(zt + m * 136 + ks * 32 + quad * 8);

    // layer 2: gelu(z1 @ W2 + b2) -> LDS
    #pragma unroll
    for (int ct = 0; ct < 8; ct++) {
        floatx4 acc = {0.f, 0.f, 0.f, 0.f};
        #pragma unroll
        for (int ks = 0; ks < 4; ks++) acc = MFMA(a2[ks], FRAG(P2, ct, ks, lane), acc);
        float bb = b2[ct * 16 + m];
        #pragma unroll
        for (int reg = 0; reg < 4; reg++)
            zt[(quad * 4 + reg) * 136 + ct * 16 + m] = f2b(gelu_exact(acc[reg] + bb));
    }
    short8 a3[4];
    #pragma unroll
    for (int ks = 0; ks < 4; ks++)
        a3[ks] = *(const short8*)(zt + m * 136 + ks * 32 + quad * 8);

    // layer 3: means = z2 @ W3 + b3  (64 cols)
    #pragma unroll
    for (int ct = 0; ct < 4; ct++) {
        floatx4 acc = {0.f, 0.f, 0.f, 0.f};
        #pragma unroll
        for (int ks = 0; ks < 4; ks++) acc = MFMA(a3[ks], FRAG(P3, ct, ks, lane), acc);
        float bb = b3[ct * 16 + m];
        #pragma unroll
        for (int reg = 0; reg < 4; reg++)
            means[(size_t)(r0 + quad * 4 + reg) * 64 + ct * 16 + m] = acc[reg] + bb;
    }
}

// ---------------- launch ----------------

extern "C" void kernel_launch(void* const* d_in, const int* in_sizes, int n_in,
                              void* d_out, int out_size, void* d_ws, size_t ws_size,
                              hipStream_t stream) {
    const float* feat  = (const float*)d_in[0];
    const int*   eidx  = (const int*)d_in[1];
    const float* W_gcn = (const float*)d_in[2];
    const float* b_gcn = (const float*)d_in[3];
    const float* W_sl  = (const float*)d_in[4];
    const float* b_sl  = (const float*)d_in[5];
    const float* W_sr  = (const float*)d_in[6];
    const float* W1    = (const float*)d_in[7];
    const float* b1    = (const float*)d_in[8];
    const float* W2    = (const float*)d_in[9];
    const float* b2    = (const float*)d_in[10];
    const float* W3    = (const float*)d_in[11];
    const float* b3    = (const float*)d_in[12];
    const float* Wv    = (const float*)d_in[13];
    const float* bv    = (const float*)d_in[14];

    const int N = in_sizes[0] / 128;
    const int E = in_sizes[1] / 2;

    char* ws = (char*)d_ws;
    size_t off = 0;
    auto alloc = [&](size_t bytes) -> void* {
        void* p = ws + off;
        off += (bytes + 255) & ~(size_t)255;
        return p;
    };
    int*   cnt     = (int*)alloc((size_t)N * 4);
    int*   row_ptr = (int*)alloc((size_t)(N + 1) * 4);
    int*   cursor  = (int*)alloc((size_t)N * 4);
    float* dinv    = (float*)alloc((size_t)N * 4);
    int*   col     = (int*)alloc((size_t)E * 4);
    unsigned short* xs   = (unsigned short*)alloc((size_t)N * 128 * 2);
    unsigned short* h1   = (unsigned short*)alloc((size_t)N * 128 * 2);
    unsigned short* mean = (unsigned short*)alloc((size_t)N * 128 * 2);
    unsigned short* Pg   = (unsigned short*)alloc(2048 * 8 * 2);
    unsigned short* Psl  = (unsigned short*)alloc(2048 * 8 * 2);
    unsigned short* Psr  = (unsigned short*)alloc(2048 * 8 * 2);
    unsigned short* P1   = (unsigned short*)alloc(2048 * 8 * 2);
    unsigned short* P2   = (unsigned short*)alloc(2048 * 8 * 2);
    unsigned short* P3   = (unsigned short*)alloc(1024 * 8 * 2);

    hipMemsetAsync(cnt, 0, (size_t)N * 4, stream);

    const int countBlocks = (E + 255) / 256;               // 2500
    const int packBlocks  = (11264 + 255) / 256;           // 44
    count_pack_kernel<<<countBlocks + packBlocks, 256, 0, stream>>>(
        eidx, E, cnt, W_gcn, W_sl, W_sr, W1, W2, W3,
        Pg, Psl, Psr, P1, P2, P3, countBlocks);

    const int NB = (N + 1023) / 1024;                      // 20
    scan_kernel<<<NB, 256, 0, stream>>>(cnt, N, E, row_ptr, cursor, dinv, NB);

    const int PS = (N + 7) / 8;                            // 2500 rows / partition
    const int fillBlocks = ((E + 2047) / 2048) * 8;        // 313 chunks x 8 XCDs = 2504
    const int gemmBlocks = ((N / 16) * 2 + 3) / 4;         // 625
    fill_gemm_kernel<<<fillBlocks + gemmBlocks, 256, 0, stream>>>(
        eidx, E, N, cursor, col, feat, dinv, Pg, xs, N, fillBlocks, PS);

    const int agrid = (N + 3) / 4;
    agg_kernel<true><<<agrid, 256, 0, stream>>>(xs, row_ptr, col, dinv, b_gcn, h1, N);
    agg_kernel<false><<<agrid, 256, 0, stream>>>(h1, row_ptr, col, dinv, nullptr, mean, N);

    sage_mlp_kernel<<<(N / 16 + 3) / 4, 256, 0, stream>>>(
        mean, h1, Psl, Psr, b_sl, P1, b1, P2, b2, P3, b3, Wv, bv,
        (float*)d_out, (float*)d_out + (size_t)N * 64, N);
}

// Round 7
// 187.433 us; speedup vs baseline: 2.2191x; 1.1808x over previous
//
#include <hip/hip_runtime.h>
#include <math.h>

// N = 20000, E = 640000, IN_DIM = HID = 128, OUT = 64
// Activations bf16 (ushort bits), accumulation fp32 via MFMA 16x16x32.
// Padded-CSR design: ONE atomic pass builds col[N][CAP]; deg lives in cnt.
// (Round-5 lesson: every device-atomic pass over E costs ~20 MB of
// memory-side write traffic (640K x 32B) -- atomics execute at the coherent
// point, not in the XCD L2. So run exactly one such pass.)

#define CAP 96   // max supported degree; E/N=32 mean, expected max ~57, P(>96)~e^-41

typedef __attribute__((ext_vector_type(8))) short short8;
typedef __attribute__((ext_vector_type(4))) float floatx4;

__device__ __forceinline__ unsigned short f2b(float f) {
    unsigned u = __float_as_uint(f);
    unsigned r = (u + 0x7fffu + ((u >> 16) & 1u)) >> 16;
    return (unsigned short)r;
}
__device__ __forceinline__ float b2f(unsigned short h) {
    return __uint_as_float(((unsigned)h) << 16);
}
__device__ __forceinline__ float b2f_lo(unsigned v) {
    return __uint_as_float(v << 16);
}
__device__ __forceinline__ float b2f_hi(unsigned v) {
    return __uint_as_float(v & 0xffff0000u);
}
__device__ __forceinline__ floatx4 MFMA(short8 a, short8 b, floatx4 c) {
    return __builtin_amdgcn_mfma_f32_16x16x32_bf16(a, b, c, 0, 0, 0);
}
__device__ __forceinline__ float gelu_exact(float x) {
    return 0.5f * x * (1.0f + erff(x * 0.70710678118654752440f));
}

// B fragment for (ct, ks) at lane: packed W layout
#define FRAG(P, ct, ks, lane) (*(const short8*)((P) + (((((ct)*4 + (ks))*64) + (lane)) << 3)))

// ---------------- weight packing + cnt zeroing (44 blocks) ----------------
// Replaces the memset dispatch; must run before fill (cnt=0) and before
// the GEMM dispatch (Pg ready). 44*256 = 11264 threads exactly.

__global__ __launch_bounds__(256) void pack_zero_kernel(
    int* __restrict__ cnt, int N,
    const float* Wg, const float* Wsl, const float* Wsr,
    const float* W1, const float* W2, const float* W3,
    unsigned short* Pg, unsigned short* Psl, unsigned short* Psr,
    unsigned short* P1, unsigned short* P2, unsigned short* P3)
{
    int t = blockIdx.x * 256 + threadIdx.x;
    for (int i = t; i < N; i += 11264) cnt[i] = 0;
    const float* W; unsigned short* P; int NC = 128; int base;
    if (t < 2048)       { W = Wg;  P = Pg;  base = t; }
    else if (t < 4096)  { W = Wsl; P = Psl; base = t - 2048; }
    else if (t < 6144)  { W = Wsr; P = Psr; base = t - 4096; }
    else if (t < 8192)  { W = W1;  P = P1;  base = t - 6144; }
    else if (t < 10240) { W = W2;  P = P2;  base = t - 8192; }
    else if (t < 11264) { W = W3;  P = P3;  base = t - 10240; NC = 64; }
    else return;
    int l  = base & 63;
    int ks = (base >> 6) & 3;
    int ct = base >> 8;
    int n  = ct * 16 + (l & 15);
    int k0 = ks * 32 + ((l >> 4) << 3);
    short8 v;
    #pragma unroll
    for (int j = 0; j < 8; j++) v[j] = (short)f2b(W[(size_t)(k0 + j) * NC + n]);
    *(short8*)(P + ((size_t)base << 3)) = v;
}

// ---------------- fill (padded CSR, ONE atomic pass) + GCN GEMM ------------
// XCD-partitioned scatter (round-4/5 win): block b = (chunk b>>3, partition
// b&7); each col line has one L2 owner. rank = atomicAdd return places the
// edge directly: col[d*CAP + rank] = src. GEMM (unscaled xs) is independent
// of cnt, so it stays fused in this dispatch and overlaps the scatter.

__global__ __launch_bounds__(256) void fill_gemm_kernel(
    const int* __restrict__ eidx, int E,
    int* __restrict__ cnt, int* __restrict__ col,
    const float* __restrict__ feat,
    const unsigned short* __restrict__ Pg,
    unsigned short* __restrict__ xs, int M, int fillBlocks, int PS)
{
    if ((int)blockIdx.x < fillBlocks) {
        int chunk = blockIdx.x >> 3;
        int p = blockIdx.x & 7;
        int lo = p * PS;
        int hi = lo + PS;
        int e0 = chunk * 2048;
        int e1 = e0 + 2048 < E ? e0 + 2048 : E;
        for (int e = e0 + (int)threadIdx.x; e < e1; e += 256) {
            int d = eidx[E + e];
            if (d >= lo && d < hi) {
                int r = atomicAdd(&cnt[d], 1);
                if (r < CAP) col[d * CAP + r] = eidx[e];
            }
        }
        return;
    }
    // GCN GEMM: wave computes 16 rows x 64 cols of xs = bf16(feat @ Wg)
    int bid = blockIdx.x - fillBlocks;
    int w = bid * 4 + (threadIdx.x >> 6);
    if (w >= (M / 16) * 2) return;
    int lane = threadIdx.x & 63;
    int m = lane & 15, quad = lane >> 4;
    int rt = w >> 1, ch = w & 1;
    const float* arow = feat + (size_t)(rt * 16 + m) * 128;
    short8 a[4];
    #pragma unroll
    for (int ks = 0; ks < 4; ks++) {
        float4 f0 = *(const float4*)(arow + ks * 32 + quad * 8);
        float4 f1 = *(const float4*)(arow + ks * 32 + quad * 8 + 4);
        short8 s;
        s[0] = (short)f2b(f0.x); s[1] = (short)f2b(f0.y);
        s[2] = (short)f2b(f0.z); s[3] = (short)f2b(f0.w);
        s[4] = (short)f2b(f1.x); s[5] = (short)f2b(f1.y);
        s[6] = (short)f2b(f1.z); s[7] = (short)f2b(f1.w);
        a[ks] = s;
    }
    #pragma unroll
    for (int ct = 0; ct < 4; ct++) {
        floatx4 acc = {0.f, 0.f, 0.f, 0.f};
        #pragma unroll
        for (int ks = 0; ks < 4; ks++)
            acc = MFMA(a[ks], FRAG(Pg, ch * 4 + ct, ks, lane), acc);
        #pragma unroll
        for (int reg = 0; reg < 4; reg++)
            xs[(size_t)(rt * 16 + quad * 4 + reg) * 128 + (ch * 4 + ct) * 16 + m] =
                f2b(acc[reg]);
    }
}

// ---------------- aggregation: padded col, contiguous per row --------------
// GCN:  h1[d] = relu(dinv_d*(sum_s dinv_s*xs[s] + dinv_d*xs[d]) + b),
//       dinv_x = rsqrt(cnt[x]+1) computed inline (no dinv array).
// SAGE: mean[d] = (1/max(deg,1)) * sum_s h1[s]

template<bool GCN>
__global__ __launch_bounds__(256) void agg_kernel(
    const unsigned short* __restrict__ X, const int* __restrict__ cnt,
    const int* __restrict__ col, const float* __restrict__ bias,
    unsigned short* __restrict__ Y, int N)
{
    int w = (int)((blockIdx.x * 256 + threadIdx.x) >> 6);
    if (w >= N) return;
    int lane = threadIdx.x & 63;
    int g = lane >> 4, t = lane & 15;
    const uint4* Xq = (const uint4*)X;

    int deg = cnt[w];
    int n = deg < CAP ? deg : CAP;
    int beg = w * CAP, end = beg + n;

    float acc[8] = {0.f, 0.f, 0.f, 0.f, 0.f, 0.f, 0.f, 0.f};

    int e = beg + g;
    for (; e + 4 < end; e += 8) {
        int s0 = col[e];
        int s1 = col[e + 4];
        float sc0 = 1.0f, sc1 = 1.0f;
        if (GCN) {
            sc0 = rsqrtf((float)(cnt[s0] + 1));
            sc1 = rsqrtf((float)(cnt[s1] + 1));
        }
        uint4 q0 = Xq[(size_t)s0 * 16 + t];
        uint4 q1 = Xq[(size_t)s1 * 16 + t];
        acc[0] = fmaf(b2f_lo(q0.x), sc0, acc[0]);
        acc[1] = fmaf(b2f_hi(q0.x), sc0, acc[1]);
        acc[2] = fmaf(b2f_lo(q0.y), sc0, acc[2]);
        acc[3] = fmaf(b2f_hi(q0.y), sc0, acc[3]);
        acc[4] = fmaf(b2f_lo(q0.z), sc0, acc[4]);
        acc[5] = fmaf(b2f_hi(q0.z), sc0, acc[5]);
        acc[6] = fmaf(b2f_lo(q0.w), sc0, acc[6]);
        acc[7] = fmaf(b2f_hi(q0.w), sc0, acc[7]);
        acc[0] = fmaf(b2f_lo(q1.x), sc1, acc[0]);
        acc[1] = fmaf(b2f_hi(q1.x), sc1, acc[1]);
        acc[2] = fmaf(b2f_lo(q1.y), sc1, acc[2]);
        acc[3] = fmaf(b2f_hi(q1.y), sc1, acc[3]);
        acc[4] = fmaf(b2f_lo(q1.z), sc1, acc[4]);
        acc[5] = fmaf(b2f_hi(q1.z), sc1, acc[5]);
        acc[6] = fmaf(b2f_lo(q1.w), sc1, acc[6]);
        acc[7] = fmaf(b2f_hi(q1.w), sc1, acc[7]);
    }
    if (e < end) {
        int s0 = col[e];
        float sc0 = GCN ? rsqrtf((float)(cnt[s0] + 1)) : 1.0f;
        uint4 q0 = Xq[(size_t)s0 * 16 + t];
        acc[0] = fmaf(b2f_lo(q0.x), sc0, acc[0]);
        acc[1] = fmaf(b2f_hi(q0.x), sc0, acc[1]);
        acc[2] = fmaf(b2f_lo(q0.y), sc0, acc[2]);
        acc[3] = fmaf(b2f_hi(q0.y), sc0, acc[3]);
        acc[4] = fmaf(b2f_lo(q0.z), sc0, acc[4]);
        acc[5] = fmaf(b2f_hi(q0.z), sc0, acc[5]);
        acc[6] = fmaf(b2f_lo(q0.w), sc0, acc[6]);
        acc[7] = fmaf(b2f_hi(q0.w), sc0, acc[7]);
    }

    // reduce across the 4 groups
    #pragma unroll
    for (int i = 0; i < 8; i++) {
        acc[i] += __shfl_xor(acc[i], 16);
        acc[i] += __shfl_xor(acc[i], 32);
    }
    if (g == 0) {
        float out[8];
        if (GCN) {
            float dw = rsqrtf((float)(deg + 1));
            uint4 q = Xq[(size_t)w * 16 + t];  // self loop
            acc[0] = fmaf(b2f_lo(q.x), dw, acc[0]);
            acc[1] = fmaf(b2f_hi(q.x), dw, acc[1]);
            acc[2] = fmaf(b2f_lo(q.y), dw, acc[2]);
            acc[3] = fmaf(b2f_hi(q.y), dw, acc[3]);
            acc[4] = fmaf(b2f_lo(q.z), dw, acc[4]);
            acc[5] = fmaf(b2f_hi(q.z), dw, acc[5]);
            acc[6] = fmaf(b2f_lo(q.w), dw, acc[6]);
            acc[7] = fmaf(b2f_hi(q.w), dw, acc[7]);
            float4 b0 = *(const float4*)(bias + t * 8);
            float4 b1 = *(const float4*)(bias + t * 8 + 4);
            out[0] = fmaxf(fmaf(acc[0], dw, b0.x), 0.f);
            out[1] = fmaxf(fmaf(acc[1], dw, b0.y), 0.f);
            out[2] = fmaxf(fmaf(acc[2], dw, b0.z), 0.f);
            out[3] = fmaxf(fmaf(acc[3], dw, b0.w), 0.f);
            out[4] = fmaxf(fmaf(acc[4], dw, b1.x), 0.f);
            out[5] = fmaxf(fmaf(acc[5], dw, b1.y), 0.f);
            out[6] = fmaxf(fmaf(acc[6], dw, b1.z), 0.f);
            out[7] = fmaxf(fmaf(acc[7], dw, b1.w), 0.f);
        } else {
            float rc = 1.0f / (float)(deg > 0 ? deg : 1);
            #pragma unroll
            for (int i = 0; i < 8; i++) out[i] = acc[i] * rc;
        }
        uint4 r;
        r.x = (unsigned)f2b(out[0]) | ((unsigned)f2b(out[1]) << 16);
        r.y = (unsigned)f2b(out[2]) | ((unsigned)f2b(out[3]) << 16);
        r.z = (unsigned)f2b(out[4]) | ((unsigned)f2b(out[5]) << 16);
        r.w = (unsigned)f2b(out[6]) | ((unsigned)f2b(out[7]) << 16);
        ((uint4*)Y)[(size_t)w * 16 + t] = r;
    }
}

// ---------------- fused SAGE + policy MLP + value head ----------------
// Per wave: 16 rows. h2 = relu(mean@Wsl + h1@Wsr + bsl) stays in LDS;
// then gelu(W1), gelu(W2), W3 -> means; value = h2@Wv+bv from C-layout.

__global__ __launch_bounds__(256) void sage_mlp_kernel(
    const unsigned short* __restrict__ mean, const unsigned short* __restrict__ h1,
    const unsigned short* __restrict__ Psl, const unsigned short* __restrict__ Psr,
    const float* __restrict__ bsl,
    const unsigned short* __restrict__ P1, const float* __restrict__ b1,
    const unsigned short* __restrict__ P2, const float* __restrict__ b2,
    const unsigned short* __restrict__ P3, const float* __restrict__ b3,
    const float* __restrict__ Wv, const float* __restrict__ bv,
    float* __restrict__ means, float* __restrict__ values, int M)
{
    __shared__ unsigned short z[4][16 * 136];
    int widx = threadIdx.x >> 6, lane = threadIdx.x & 63;
    int w = blockIdx.x * 4 + widx;
    if (w >= M / 16) return;
    int m = lane & 15, quad = lane >> 4;
    unsigned short* zt = &z[widx][0];
    int r0 = w * 16;

    short8 am[4], ar[4];
    #pragma unroll
    for (int ks = 0; ks < 4; ks++) {
        am[ks] = *(const short8*)(mean + (size_t)(r0 + m) * 128 + ks * 32 + quad * 8);
        ar[ks] = *(const short8*)(h1   + (size_t)(r0 + m) * 128 + ks * 32 + quad * 8);
    }

    // SAGE layer: h2 -> LDS (bf16) + value-head partials from C-layout
    float vpart[4] = {0.f, 0.f, 0.f, 0.f};
    #pragma unroll
    for (int ct = 0; ct < 8; ct++) {
        floatx4 acc = {0.f, 0.f, 0.f, 0.f};
        #pragma unroll
        for (int ks = 0; ks < 4; ks++) acc = MFMA(am[ks], FRAG(Psl, ct, ks, lane), acc);
        #pragma unroll
        for (int ks = 0; ks < 4; ks++) acc = MFMA(ar[ks], FRAG(Psr, ct, ks, lane), acc);
        float bb = bsl[ct * 16 + m];
        float wv = Wv[ct * 16 + m];
        #pragma unroll
        for (int reg = 0; reg < 4; reg++) {
            float o = fmaxf(acc[reg] + bb, 0.f);
            vpart[reg] = fmaf(o, wv, vpart[reg]);
            zt[(quad * 4 + reg) * 136 + ct * 16 + m] = f2b(o);
        }
    }
    // value: reduce across m-lanes within each quad
    #pragma unroll
    for (int off = 1; off <= 8; off <<= 1) {
        #pragma unroll
        for (int reg = 0; reg < 4; reg++)
            vpart[reg] += __shfl_xor(vpart[reg], off);
    }
    if (m == 0) {
        float bvv = bv[0];
        #pragma unroll
        for (int reg = 0; reg < 4; reg++)
            values[r0 + quad * 4 + reg] = vpart[reg] + bvv;
    }

    short8 a1[4];
    #pragma unroll
    for (int ks = 0; ks < 4; ks++)
        a1[ks] = *(const short8*)(zt + m * 136 + ks * 32 + quad * 8);

    // layer 1: gelu(h2 @ W1 + b1) -> LDS
    #pragma unroll
    for (int ct = 0; ct < 8; ct++) {
        floatx4 acc = {0.f, 0.f, 0.f, 0.f};
        #pragma unroll
        for (int ks = 0; ks < 4; ks++) acc = MFMA(a1[ks], FRAG(P1, ct, ks, lane), acc);
        float bb = b1[ct * 16 + m];
        #pragma unroll
        for (int reg = 0; reg < 4; reg++)
            zt[(quad * 4 + reg) * 136 + ct * 16 + m] = f2b(gelu_exact(acc[reg] + bb));
    }
    short8 a2[4];
    #pragma unroll
    for (int ks = 0; ks < 4; ks++)
        a2[ks] = *(const short8*)(zt + m * 136 + ks * 32 + quad * 8);

    // layer 2: gelu(z1 @ W2 + b2) -> LDS
    #pragma unroll
    for (int ct = 0; ct < 8; ct++) {
        floatx4 acc = {0.f, 0.f, 0.f, 0.f};
        #pragma unroll
        for (int ks = 0; ks < 4; ks++) acc = MFMA(a2[ks], FRAG(P2, ct, ks, lane), acc);
        float bb = b2[ct * 16 + m];
        #pragma unroll
        for (int reg = 0; reg < 4; reg++)
            zt[(quad * 4 + reg) * 136 + ct * 16 + m] = f2b(gelu_exact(acc[reg] + bb));
    }
    short8 a3[4];
    #pragma unroll
    for (int ks = 0; ks < 4; ks++)
        a3[ks] = *(const short8*)(zt + m * 136 + ks * 32 + quad * 8);

    // layer 3: means = z2 @ W3 + b3  (64 cols)
    #pragma unroll
    for (int ct = 0; ct < 4; ct++) {
        floatx4 acc = {0.f, 0.f, 0.f, 0.f};
        #pragma unroll
        for (int ks = 0; ks < 4; ks++) acc = MFMA(a3[ks], FRAG(P3, ct, ks, lane), acc);
        float bb = b3[ct * 16 + m];
        #pragma unroll
        for (int reg = 0; reg < 4; reg++)
            means[(size_t)(r0 + quad * 4 + reg) * 64 + ct * 16 + m] = acc[reg] + bb;
    }
}

// ---------------- launch ----------------

extern "C" void kernel_launch(void* const* d_in, const int* in_sizes, int n_in,
                              void* d_out, int out_size, void* d_ws, size_t ws_size,
                              hipStream_t stream) {
    const float* feat  = (const float*)d_in[0];
    const int*   eidx  = (const int*)d_in[1];
    const float* W_gcn = (const float*)d_in[2];
    const float* b_gcn = (const float*)d_in[3];
    const float* W_sl  = (const float*)d_in[4];
    const float* b_sl  = (const float*)d_in[5];
    const float* W_sr  = (const float*)d_in[6];
    const float* W1    = (const float*)d_in[7];
    const float* b1    = (const float*)d_in[8];
    const float* W2    = (const float*)d_in[9];
    const float* b2    = (const float*)d_in[10];
    const float* W3    = (const float*)d_in[11];
    const float* b3    = (const float*)d_in[12];
    const float* Wv    = (const float*)d_in[13];
    const float* bv    = (const float*)d_in[14];

    const int N = in_sizes[0] / 128;
    const int E = in_sizes[1] / 2;

    char* ws = (char*)d_ws;
    size_t off = 0;
    auto alloc = [&](size_t bytes) -> void* {
        void* p = ws + off;
        off += (bytes + 255) & ~(size_t)255;
        return p;
    };
    int*   cnt = (int*)alloc((size_t)N * 4);
    int*   col = (int*)alloc((size_t)N * CAP * 4);         // padded CSR, 7.68 MB
    unsigned short* xs   = (unsigned short*)alloc((size_t)N * 128 * 2);
    unsigned short* h1   = (unsigned short*)alloc((size_t)N * 128 * 2);
    unsigned short* mean = (unsigned short*)alloc((size_t)N * 128 * 2);
    unsigned short* Pg   = (unsigned short*)alloc(2048 * 8 * 2);
    unsigned short* Psl  = (unsigned short*)alloc(2048 * 8 * 2);
    unsigned short* Psr  = (unsigned short*)alloc(2048 * 8 * 2);
    unsigned short* P1   = (unsigned short*)alloc(2048 * 8 * 2);
    unsigned short* P2   = (unsigned short*)alloc(2048 * 8 * 2);
    unsigned short* P3   = (unsigned short*)alloc(1024 * 8 * 2);

    // 1: pack weights + zero cnt (replaces memset dispatch)
    pack_zero_kernel<<<44, 256, 0, stream>>>(
        cnt, N, W_gcn, W_sl, W_sr, W1, W2, W3,
        Pg, Psl, Psr, P1, P2, P3);

    // 2: padded-CSR fill (one atomic pass, XCD-partitioned) + GCN GEMM
    const int PS = (N + 7) / 8;                            // 2500 rows / partition
    const int fillBlocks = ((E + 2047) / 2048) * 8;        // 313 chunks x 8 = 2504
    const int gemmBlocks = ((N / 16) * 2 + 3) / 4;         // 625
    fill_gemm_kernel<<<fillBlocks + gemmBlocks, 256, 0, stream>>>(
        eidx, E, cnt, col, feat, Pg, xs, N, fillBlocks, PS);

    // 3+4: aggregations
    const int agrid = (N + 3) / 4;
    agg_kernel<true><<<agrid, 256, 0, stream>>>(xs, cnt, col, b_gcn, h1, N);
    agg_kernel<false><<<agrid, 256, 0, stream>>>(h1, cnt, col, nullptr, mean, N);

    // 5: fused SAGE + MLP + value head
    sage_mlp_kernel<<<(N / 16 + 3) / 4, 256, 0, stream>>>(
        mean, h1, Psl, Psr, b_sl, P1, b1, P2, b2, P3, b3, Wv, bv,
        (float*)d_out, (float*)d_out + (size_t)N * 64, N);
}

// Round 8
// 180.739 us; speedup vs baseline: 2.3013x; 1.0370x over previous
//
#include <hip/hip_runtime.h>
#include <math.h>

// N = 20000, E = 640000, IN_DIM = HID = 128, OUT = 64
// Activations bf16 (ushort bits), accumulation fp32 via MFMA 16x16x32.
// Padded-CSR design: ONE atomic pass builds col[N][CAP]; deg lives in cnt.
// (Round-5 lesson: every device-atomic pass over E costs ~20 MB of
// memory-side write traffic -- atomics execute at the coherent point.)
// Round-7 fusion: SAGE mean is row-local to its MLP tile -> aggregate
// into LDS inside the MLP kernel; drop the mean buffer + one dispatch.

#define CAP 96   // max supported degree; E/N=32 mean, expected max ~57, P(>96)~e^-41

typedef __attribute__((ext_vector_type(8))) short short8;
typedef __attribute__((ext_vector_type(4))) float floatx4;

__device__ __forceinline__ unsigned short f2b(float f) {
    unsigned u = __float_as_uint(f);
    unsigned r = (u + 0x7fffu + ((u >> 16) & 1u)) >> 16;
    return (unsigned short)r;
}
__device__ __forceinline__ float b2f(unsigned short h) {
    return __uint_as_float(((unsigned)h) << 16);
}
__device__ __forceinline__ float b2f_lo(unsigned v) {
    return __uint_as_float(v << 16);
}
__device__ __forceinline__ float b2f_hi(unsigned v) {
    return __uint_as_float(v & 0xffff0000u);
}
__device__ __forceinline__ floatx4 MFMA(short8 a, short8 b, floatx4 c) {
    return __builtin_amdgcn_mfma_f32_16x16x32_bf16(a, b, c, 0, 0, 0);
}
__device__ __forceinline__ float gelu_exact(float x) {
    return 0.5f * x * (1.0f + erff(x * 0.70710678118654752440f));
}

// B fragment for (ct, ks) at lane: packed W layout
#define FRAG(P, ct, ks, lane) (*(const short8*)((P) + (((((ct)*4 + (ks))*64) + (lane)) << 3)))

// ---------------- weight packing + cnt zeroing (44 blocks) ----------------

__global__ __launch_bounds__(256) void pack_zero_kernel(
    int* __restrict__ cnt, int N,
    const float* Wg, const float* Wsl, const float* Wsr,
    const float* W1, const float* W2, const float* W3,
    unsigned short* Pg, unsigned short* Psl, unsigned short* Psr,
    unsigned short* P1, unsigned short* P2, unsigned short* P3)
{
    int t = blockIdx.x * 256 + threadIdx.x;
    for (int i = t; i < N; i += 11264) cnt[i] = 0;
    const float* W; unsigned short* P; int NC = 128; int base;
    if (t < 2048)       { W = Wg;  P = Pg;  base = t; }
    else if (t < 4096)  { W = Wsl; P = Psl; base = t - 2048; }
    else if (t < 6144)  { W = Wsr; P = Psr; base = t - 4096; }
    else if (t < 8192)  { W = W1;  P = P1;  base = t - 6144; }
    else if (t < 10240) { W = W2;  P = P2;  base = t - 8192; }
    else if (t < 11264) { W = W3;  P = P3;  base = t - 10240; NC = 64; }
    else return;
    int l  = base & 63;
    int ks = (base >> 6) & 3;
    int ct = base >> 8;
    int n  = ct * 16 + (l & 15);
    int k0 = ks * 32 + ((l >> 4) << 3);
    short8 v;
    #pragma unroll
    for (int j = 0; j < 8; j++) v[j] = (short)f2b(W[(size_t)(k0 + j) * NC + n]);
    *(short8*)(P + ((size_t)base << 3)) = v;
}

// ---------------- fill (padded CSR, ONE atomic pass) + GCN GEMM ------------
// XCD-partitioned scatter (round-4/5 win): block b = (chunk b>>3, partition
// b&7). GEMM (unscaled xs) is independent of cnt -> fused, overlaps scatter.

__global__ __launch_bounds__(256) void fill_gemm_kernel(
    const int* __restrict__ eidx, int E,
    int* __restrict__ cnt, int* __restrict__ col,
    const float* __restrict__ feat,
    const unsigned short* __restrict__ Pg,
    unsigned short* __restrict__ xs, int M, int fillBlocks, int PS)
{
    if ((int)blockIdx.x < fillBlocks) {
        int chunk = blockIdx.x >> 3;
        int p = blockIdx.x & 7;
        int lo = p * PS;
        int hi = lo + PS;
        int e0 = chunk * 2048;
        int e1 = e0 + 2048 < E ? e0 + 2048 : E;
        for (int e = e0 + (int)threadIdx.x; e < e1; e += 256) {
            int d = eidx[E + e];
            if (d >= lo && d < hi) {
                int r = atomicAdd(&cnt[d], 1);
                if (r < CAP) col[d * CAP + r] = eidx[e];
            }
        }
        return;
    }
    // GCN GEMM: wave computes 16 rows x 64 cols of xs = bf16(feat @ Wg)
    int bid = blockIdx.x - fillBlocks;
    int w = bid * 4 + (threadIdx.x >> 6);
    if (w >= (M / 16) * 2) return;
    int lane = threadIdx.x & 63;
    int m = lane & 15, quad = lane >> 4;
    int rt = w >> 1, ch = w & 1;
    const float* arow = feat + (size_t)(rt * 16 + m) * 128;
    short8 a[4];
    #pragma unroll
    for (int ks = 0; ks < 4; ks++) {
        float4 f0 = *(const float4*)(arow + ks * 32 + quad * 8);
        float4 f1 = *(const float4*)(arow + ks * 32 + quad * 8 + 4);
        short8 s;
        s[0] = (short)f2b(f0.x); s[1] = (short)f2b(f0.y);
        s[2] = (short)f2b(f0.z); s[3] = (short)f2b(f0.w);
        s[4] = (short)f2b(f1.x); s[5] = (short)f2b(f1.y);
        s[6] = (short)f2b(f1.z); s[7] = (short)f2b(f1.w);
        a[ks] = s;
    }
    #pragma unroll
    for (int ct = 0; ct < 4; ct++) {
        floatx4 acc = {0.f, 0.f, 0.f, 0.f};
        #pragma unroll
        for (int ks = 0; ks < 4; ks++)
            acc = MFMA(a[ks], FRAG(Pg, ch * 4 + ct, ks, lane), acc);
        #pragma unroll
        for (int reg = 0; reg < 4; reg++)
            xs[(size_t)(rt * 16 + quad * 4 + reg) * 128 + (ch * 4 + ct) * 16 + m] =
                f2b(acc[reg]);
    }
}

// ---------------- GCN aggregation (unchanged) ----------------
// h1[d] = relu(dinv_d*(sum_s dinv_s*xs[s] + dinv_d*xs[d]) + b)

__global__ __launch_bounds__(256) void agg_gcn_kernel(
    const unsigned short* __restrict__ X, const int* __restrict__ cnt,
    const int* __restrict__ col, const float* __restrict__ bias,
    unsigned short* __restrict__ Y, int N)
{
    int w = (int)((blockIdx.x * 256 + threadIdx.x) >> 6);
    if (w >= N) return;
    int lane = threadIdx.x & 63;
    int g = lane >> 4, t = lane & 15;
    const uint4* Xq = (const uint4*)X;

    int deg = cnt[w];
    int n = deg < CAP ? deg : CAP;
    int beg = w * CAP, end = beg + n;

    float acc[8] = {0.f, 0.f, 0.f, 0.f, 0.f, 0.f, 0.f, 0.f};

    int e = beg + g;
    for (; e + 4 < end; e += 8) {
        int s0 = col[e];
        int s1 = col[e + 4];
        float sc0 = rsqrtf((float)(cnt[s0] + 1));
        float sc1 = rsqrtf((float)(cnt[s1] + 1));
        uint4 q0 = Xq[(size_t)s0 * 16 + t];
        uint4 q1 = Xq[(size_t)s1 * 16 + t];
        acc[0] = fmaf(b2f_lo(q0.x), sc0, acc[0]);
        acc[1] = fmaf(b2f_hi(q0.x), sc0, acc[1]);
        acc[2] = fmaf(b2f_lo(q0.y), sc0, acc[2]);
        acc[3] = fmaf(b2f_hi(q0.y), sc0, acc[3]);
        acc[4] = fmaf(b2f_lo(q0.z), sc0, acc[4]);
        acc[5] = fmaf(b2f_hi(q0.z), sc0, acc[5]);
        acc[6] = fmaf(b2f_lo(q0.w), sc0, acc[6]);
        acc[7] = fmaf(b2f_hi(q0.w), sc0, acc[7]);
        acc[0] = fmaf(b2f_lo(q1.x), sc1, acc[0]);
        acc[1] = fmaf(b2f_hi(q1.x), sc1, acc[1]);
        acc[2] = fmaf(b2f_lo(q1.y), sc1, acc[2]);
        acc[3] = fmaf(b2f_hi(q1.y), sc1, acc[3]);
        acc[4] = fmaf(b2f_lo(q1.z), sc1, acc[4]);
        acc[5] = fmaf(b2f_hi(q1.z), sc1, acc[5]);
        acc[6] = fmaf(b2f_lo(q1.w), sc1, acc[6]);
        acc[7] = fmaf(b2f_hi(q1.w), sc1, acc[7]);
    }
    if (e < end) {
        int s0 = col[e];
        float sc0 = rsqrtf((float)(cnt[s0] + 1));
        uint4 q0 = Xq[(size_t)s0 * 16 + t];
        acc[0] = fmaf(b2f_lo(q0.x), sc0, acc[0]);
        acc[1] = fmaf(b2f_hi(q0.x), sc0, acc[1]);
        acc[2] = fmaf(b2f_lo(q0.y), sc0, acc[2]);
        acc[3] = fmaf(b2f_hi(q0.y), sc0, acc[3]);
        acc[4] = fmaf(b2f_lo(q0.z), sc0, acc[4]);
        acc[5] = fmaf(b2f_hi(q0.z), sc0, acc[5]);
        acc[6] = fmaf(b2f_lo(q0.w), sc0, acc[6]);
        acc[7] = fmaf(b2f_hi(q0.w), sc0, acc[7]);
    }

    #pragma unroll
    for (int i = 0; i < 8; i++) {
        acc[i] += __shfl_xor(acc[i], 16);
        acc[i] += __shfl_xor(acc[i], 32);
    }
    if (g == 0) {
        float dw = rsqrtf((float)(deg + 1));
        uint4 q = Xq[(size_t)w * 16 + t];  // self loop
        acc[0] = fmaf(b2f_lo(q.x), dw, acc[0]);
        acc[1] = fmaf(b2f_hi(q.x), dw, acc[1]);
        acc[2] = fmaf(b2f_lo(q.y), dw, acc[2]);
        acc[3] = fmaf(b2f_hi(q.y), dw, acc[3]);
        acc[4] = fmaf(b2f_lo(q.z), dw, acc[4]);
        acc[5] = fmaf(b2f_hi(q.z), dw, acc[5]);
        acc[6] = fmaf(b2f_lo(q.w), dw, acc[6]);
        acc[7] = fmaf(b2f_hi(q.w), dw, acc[7]);
        float4 b0 = *(const float4*)(bias + t * 8);
        float4 b1 = *(const float4*)(bias + t * 8 + 4);
        float out[8];
        out[0] = fmaxf(fmaf(acc[0], dw, b0.x), 0.f);
        out[1] = fmaxf(fmaf(acc[1], dw, b0.y), 0.f);
        out[2] = fmaxf(fmaf(acc[2], dw, b0.z), 0.f);
        out[3] = fmaxf(fmaf(acc[3], dw, b0.w), 0.f);
        out[4] = fmaxf(fmaf(acc[4], dw, b1.x), 0.f);
        out[5] = fmaxf(fmaf(acc[5], dw, b1.y), 0.f);
        out[6] = fmaxf(fmaf(acc[6], dw, b1.z), 0.f);
        out[7] = fmaxf(fmaf(acc[7], dw, b1.w), 0.f);
        uint4 r;
        r.x = (unsigned)f2b(out[0]) | ((unsigned)f2b(out[1]) << 16);
        r.y = (unsigned)f2b(out[2]) | ((unsigned)f2b(out[3]) << 16);
        r.z = (unsigned)f2b(out[4]) | ((unsigned)f2b(out[5]) << 16);
        r.w = (unsigned)f2b(out[6]) | ((unsigned)f2b(out[7]) << 16);
        ((uint4*)Y)[(size_t)w * 16 + t] = r;
    }
}

// ---------------- fused SAGE-mean + SAGE layer + MLP + value head ----------
// One block per 16-row tile. Phase A: wave widx mean-aggregates rows
// widx*4..+3 of h1 into LDS zm (bf16). Phase B: 4 waves cooperate on the
// tile's MLP: each wave owns 2 of 8 ct-tiles per 128-col layer (1 of 4 in
// layer 3), ping-ponging zm <-> za with barriers. Value head: per-wave
// fp32 partials -> LDS vp -> summed by threads 0..15.

__global__ __launch_bounds__(256) void sage_fused_kernel(
    const unsigned short* __restrict__ h1, const int* __restrict__ cnt,
    const int* __restrict__ col,
    const unsigned short* __restrict__ Psl, const unsigned short* __restrict__ Psr,
    const float* __restrict__ bsl,
    const unsigned short* __restrict__ P1, const float* __restrict__ b1,
    const unsigned short* __restrict__ P2, const float* __restrict__ b2,
    const unsigned short* __restrict__ P3, const float* __restrict__ b3,
    const float* __restrict__ Wv, const float* __restrict__ bv,
    float* __restrict__ means, float* __restrict__ values, int N)
{
    __shared__ unsigned short zm[16 * 136];   // mean, later z1
    __shared__ unsigned short za[16 * 136];   // h2, later z2
    __shared__ float vp[16][4];               // value partials [row][wave]
    int widx = threadIdx.x >> 6, lane = threadIdx.x & 63;
    int r0 = blockIdx.x * 16;
    if (r0 >= N) return;
    int g = lane >> 4, t = lane & 15;
    const uint4* Xq = (const uint4*)h1;

    // ---- phase A: mean aggregation, wave widx -> rows widx*4 .. +3 ----
    for (int rr = 0; rr < 4; rr++) {
        int w = r0 + widx * 4 + rr;
        int deg = cnt[w];
        int n = deg < CAP ? deg : CAP;
        int beg = w * CAP, end = beg + n;
        float acc[8] = {0.f, 0.f, 0.f, 0.f, 0.f, 0.f, 0.f, 0.f};
        int e = beg + g;
        for (; e + 4 < end; e += 8) {
            int s0 = col[e];
            int s1 = col[e + 4];
            uint4 q0 = Xq[(size_t)s0 * 16 + t];
            uint4 q1 = Xq[(size_t)s1 * 16 + t];
            acc[0] += b2f_lo(q0.x); acc[1] += b2f_hi(q0.x);
            acc[2] += b2f_lo(q0.y); acc[3] += b2f_hi(q0.y);
            acc[4] += b2f_lo(q0.z); acc[5] += b2f_hi(q0.z);
            acc[6] += b2f_lo(q0.w); acc[7] += b2f_hi(q0.w);
            acc[0] += b2f_lo(q1.x); acc[1] += b2f_hi(q1.x);
            acc[2] += b2f_lo(q1.y); acc[3] += b2f_hi(q1.y);
            acc[4] += b2f_lo(q1.z); acc[5] += b2f_hi(q1.z);
            acc[6] += b2f_lo(q1.w); acc[7] += b2f_hi(q1.w);
        }
        if (e < end) {
            int s0 = col[e];
            uint4 q0 = Xq[(size_t)s0 * 16 + t];
            acc[0] += b2f_lo(q0.x); acc[1] += b2f_hi(q0.x);
            acc[2] += b2f_lo(q0.y); acc[3] += b2f_hi(q0.y);
            acc[4] += b2f_lo(q0.z); acc[5] += b2f_hi(q0.z);
            acc[6] += b2f_lo(q0.w); acc[7] += b2f_hi(q0.w);
        }
        #pragma unroll
        for (int i = 0; i < 8; i++) {
            acc[i] += __shfl_xor(acc[i], 16);
            acc[i] += __shfl_xor(acc[i], 32);
        }
        if (g == 0) {
            float rc = 1.0f / (float)(deg > 0 ? deg : 1);
            uint4 r;
            r.x = (unsigned)f2b(acc[0] * rc) | ((unsigned)f2b(acc[1] * rc) << 16);
            r.y = (unsigned)f2b(acc[2] * rc) | ((unsigned)f2b(acc[3] * rc) << 16);
            r.z = (unsigned)f2b(acc[4] * rc) | ((unsigned)f2b(acc[5] * rc) << 16);
            r.w = (unsigned)f2b(acc[6] * rc) | ((unsigned)f2b(acc[7] * rc) << 16);
            *(uint4*)(zm + (widx * 4 + rr) * 136 + t * 8) = r;
        }
    }
    __syncthreads();   // B1: zm (mean) complete

    int m = t, quad = g;

    // A fragments: mean from LDS, root h1 from global
    short8 am[4], ar[4];
    #pragma unroll
    for (int ks = 0; ks < 4; ks++) {
        am[ks] = *(const short8*)(zm + m * 136 + ks * 32 + quad * 8);
        ar[ks] = *(const short8*)(h1 + (size_t)(r0 + m) * 128 + ks * 32 + quad * 8);
    }

    // SAGE layer: wave widx -> ct = 2*widx, 2*widx+1; h2 -> za; value partials
    float vpart[4] = {0.f, 0.f, 0.f, 0.f};
    #pragma unroll
    for (int ci = 0; ci < 2; ci++) {
        int ct = widx * 2 + ci;
        floatx4 acc = {0.f, 0.f, 0.f, 0.f};
        #pragma unroll
        for (int ks = 0; ks < 4; ks++) acc = MFMA(am[ks], FRAG(Psl, ct, ks, lane), acc);
        #pragma unroll
        for (int ks = 0; ks < 4; ks++) acc = MFMA(ar[ks], FRAG(Psr, ct, ks, lane), acc);
        float bb = bsl[ct * 16 + m];
        float wvv = Wv[ct * 16 + m];
        #pragma unroll
        for (int reg = 0; reg < 4; reg++) {
            float o = fmaxf(acc[reg] + bb, 0.f);
            vpart[reg] = fmaf(o, wvv, vpart[reg]);
            za[(quad * 4 + reg) * 136 + ct * 16 + m] = f2b(o);
        }
    }
    #pragma unroll
    for (int off = 1; off <= 8; off <<= 1) {
        #pragma unroll
        for (int reg = 0; reg < 4; reg++)
            vpart[reg] += __shfl_xor(vpart[reg], off);
    }
    if (m == 0) {
        #pragma unroll
        for (int reg = 0; reg < 4; reg++)
            vp[quad * 4 + reg][widx] = vpart[reg];
    }
    __syncthreads();   // B2: za (h2), vp complete

    if (threadIdx.x < 16) {
        float v = vp[threadIdx.x][0] + vp[threadIdx.x][1]
                + vp[threadIdx.x][2] + vp[threadIdx.x][3];
        values[r0 + threadIdx.x] = v + bv[0];
    }

    // layer 1: za -> zm
    short8 a1[4];
    #pragma unroll
    for (int ks = 0; ks < 4; ks++)
        a1[ks] = *(const short8*)(za + m * 136 + ks * 32 + quad * 8);
    #pragma unroll
    for (int ci = 0; ci < 2; ci++) {
        int ct = widx * 2 + ci;
        floatx4 acc = {0.f, 0.f, 0.f, 0.f};
        #pragma unroll
        for (int ks = 0; ks < 4; ks++) acc = MFMA(a1[ks], FRAG(P1, ct, ks, lane), acc);
        float bb = b1[ct * 16 + m];
        #pragma unroll
        for (int reg = 0; reg < 4; reg++)
            zm[(quad * 4 + reg) * 136 + ct * 16 + m] = f2b(gelu_exact(acc[reg] + bb));
    }
    __syncthreads();   // B3: zm (z1) complete

    // layer 2: zm -> za
    short8 a2[4];
    #pragma unroll
    for (int ks = 0; ks < 4; ks++)
        a2[ks] = *(const short8*)(zm + m * 136 + ks * 32 + quad * 8);
    #pragma unroll
    for (int ci = 0; ci < 2; ci++) {
        int ct = widx * 2 + ci;
        floatx4 acc = {0.f, 0.f, 0.f, 0.f};
        #pragma unroll
        for (int ks = 0; ks < 4; ks++) acc = MFMA(a2[ks], FRAG(P2, ct, ks, lane), acc);
        float bb = b2[ct * 16 + m];
        #pragma unroll
        for (int reg = 0; reg < 4; reg++)
            za[(quad * 4 + reg) * 136 + ct * 16 + m] = f2b(gelu_exact(acc[reg] + bb));
    }
    __syncthreads();   // B4: za (z2) complete

    // layer 3 (64 cols): wave widx -> ct = widx; za -> means (global)
    short8 a3[4];
    #pragma unroll
    for (int ks = 0; ks < 4; ks++)
        a3[ks] = *(const short8*)(za + m * 136 + ks * 32 + quad * 8);
    {
        int ct = widx;
        floatx4 acc = {0.f, 0.f, 0.f, 0.f};
        #pragma unroll
        for (int ks = 0; ks < 4; ks++) acc = MFMA(a3[ks], FRAG(P3, ct, ks, lane), acc);
        float bb = b3[ct * 16 + m];
        #pragma unroll
        for (int reg = 0; reg < 4; reg++)
            means[(size_t)(r0 + quad * 4 + reg) * 64 + ct * 16 + m] = acc[reg] + bb;
    }
}

// ---------------- launch ----------------

extern "C" void kernel_launch(void* const* d_in, const int* in_sizes, int n_in,
                              void* d_out, int out_size, void* d_ws, size_t ws_size,
                              hipStream_t stream) {
    const float* feat  = (const float*)d_in[0];
    const int*   eidx  = (const int*)d_in[1];
    const float* W_gcn = (const float*)d_in[2];
    const float* b_gcn = (const float*)d_in[3];
    const float* W_sl  = (const float*)d_in[4];
    const float* b_sl  = (const float*)d_in[5];
    const float* W_sr  = (const float*)d_in[6];
    const float* W1    = (const float*)d_in[7];
    const float* b1    = (const float*)d_in[8];
    const float* W2    = (const float*)d_in[9];
    const float* b2    = (const float*)d_in[10];
    const float* W3    = (const float*)d_in[11];
    const float* b3    = (const float*)d_in[12];
    const float* Wv    = (const float*)d_in[13];
    const float* bv    = (const float*)d_in[14];

    const int N = in_sizes[0] / 128;
    const int E = in_sizes[1] / 2;

    char* ws = (char*)d_ws;
    size_t off = 0;
    auto alloc = [&](size_t bytes) -> void* {
        void* p = ws + off;
        off += (bytes + 255) & ~(size_t)255;
        return p;
    };
    int*   cnt = (int*)alloc((size_t)N * 4);
    int*   col = (int*)alloc((size_t)N * CAP * 4);         // padded CSR, 7.68 MB
    unsigned short* xs   = (unsigned short*)alloc((size_t)N * 128 * 2);
    unsigned short* h1   = (unsigned short*)alloc((size_t)N * 128 * 2);
    unsigned short* Pg   = (unsigned short*)alloc(2048 * 8 * 2);
    unsigned short* Psl  = (unsigned short*)alloc(2048 * 8 * 2);
    unsigned short* Psr  = (unsigned short*)alloc(2048 * 8 * 2);
    unsigned short* P1   = (unsigned short*)alloc(2048 * 8 * 2);
    unsigned short* P2   = (unsigned short*)alloc(2048 * 8 * 2);
    unsigned short* P3   = (unsigned short*)alloc(1024 * 8 * 2);

    // 1: pack weights + zero cnt
    pack_zero_kernel<<<44, 256, 0, stream>>>(
        cnt, N, W_gcn, W_sl, W_sr, W1, W2, W3,
        Pg, Psl, Psr, P1, P2, P3);

    // 2: padded-CSR fill (one atomic pass, XCD-partitioned) + GCN GEMM
    const int PS = (N + 7) / 8;                            // 2500 rows / partition
    const int fillBlocks = ((E + 2047) / 2048) * 8;        // 313 chunks x 8 = 2504
    const int gemmBlocks = ((N / 16) * 2 + 3) / 4;         // 625
    fill_gemm_kernel<<<fillBlocks + gemmBlocks, 256, 0, stream>>>(
        eidx, E, cnt, col, feat, Pg, xs, N, fillBlocks, PS);

    // 3: GCN aggregation
    const int agrid = (N + 3) / 4;
    agg_gcn_kernel<<<agrid, 256, 0, stream>>>(xs, cnt, col, b_gcn, h1, N);

    // 4: fused SAGE mean + SAGE layer + MLP + value head
    sage_fused_kernel<<<(N + 15) / 16, 256, 0, stream>>>(
        h1, cnt, col, Psl, Psr, b_sl, P1, b1, P2, b2, P3, b3, Wv, bv,
        (float*)d_out, (float*)d_out + (size_t)N * 64, N);
}